// Round 7
// baseline (316.767 us; speedup 1.0000x reference)
//
#include <hip/hip_runtime.h>
#include <hip/hip_bf16.h>
#include <math.h>

#define EMBED 1024
#define HEADS 16
#define HDIM 64
#define FFDIM 4096
#define BATCH 8
#define TLEN 128
#define CARRY 4096
#define SEQA (CARRY + TLEN)   // 4224
#define MROWS (BATCH * TLEN)  // 1024
#define NSPLIT 8

typedef __attribute__((ext_vector_type(8))) short bf16x8;
typedef __attribute__((ext_vector_type(4))) float f32x4;
typedef unsigned short u16;

static __device__ __forceinline__ u16 f2b(float v) {
    __hip_bfloat16 h = __float2bfloat16(v);
    return *reinterpret_cast<u16*>(&h);
}

typedef const __attribute__((address_space(1))) unsigned int g_u32;
typedef __attribute__((address_space(3))) unsigned int l_u32;
static __device__ __forceinline__ void gl16(const void* g, void* l) {
    __builtin_amdgcn_global_load_lds((g_u32*)g, (l_u32*)l, 16, 0, 0);
}

// barrier that does NOT drain vmcnt (stores/prefetch loads stay in flight)
static __device__ __forceinline__ void bar_lgkm() {
    asm volatile("s_waitcnt lgkmcnt(0)" ::: "memory");
    __builtin_amdgcn_s_barrier();
    __builtin_amdgcn_sched_barrier(0);
}
static __device__ __forceinline__ void bar_plain() {
    __builtin_amdgcn_sched_barrier(0);
    __builtin_amdgcn_s_barrier();
}

// ---------------- carry copy (fallback path only) ----------------
__global__ void copy_carry_kernel(const float4* __restrict__ kc, const float4* __restrict__ vc,
                                  float4* __restrict__ k_all, float4* __restrict__ v_all) {
    const size_t total = (size_t)BATCH * HEADS * CARRY * HDIM / 4;
    const size_t DH = (size_t)SEQA * HDIM / 4;
    for (size_t e = (size_t)blockIdx.x * blockDim.x + threadIdx.x; e < total;
         e += (size_t)gridDim.x * blockDim.x) {
        size_t bh = e >> 16;
        size_t rem = e & 65535;
        size_t d = bh * DH + rem;
        k_all[d] = kc[e];
        v_all[d] = vc[e];
    }
}

// ---------------- LayerNorm fp32 in -> bf16 out ----------------
__global__ __launch_bounds__(256) void ln_kernel(const float* __restrict__ in,
                                                 const float* __restrict__ scale,
                                                 const float* __restrict__ bias,
                                                 u16* __restrict__ out) {
    int row = blockIdx.x;
    int tid = threadIdx.x;
    const float4* rin = (const float4*)(in + (size_t)row * EMBED);
    float4 v = rin[tid];
    float s = v.x + v.y + v.z + v.w;
    float s2 = v.x * v.x + v.y * v.y + v.z * v.z + v.w * v.w;
    for (int o = 32; o > 0; o >>= 1) {
        s += __shfl_down(s, o, 64);
        s2 += __shfl_down(s2, o, 64);
    }
    __shared__ float ls[8], ls2[8];
    int wid = tid >> 6, lane = tid & 63;
    if (lane == 0) { ls[wid] = s; ls2[wid] = s2; }
    __syncthreads();
    if (tid == 0) {
        float S = 0.f, S2 = 0.f;
        for (int i = 0; i < 4; i++) { S += ls[i]; S2 += ls2[i]; }
        float mu = S * (1.0f / EMBED);
        float var = S2 * (1.0f / EMBED) - mu * mu;
        ls[0] = mu;
        ls2[0] = rsqrtf(var + 1e-5f);
    }
    __syncthreads();
    float mu = ls[0], rstd = ls2[0];
    float sc[4], bi[4], xin[4];
    *(float4*)sc = ((const float4*)scale)[tid];
    *(float4*)bi = ((const float4*)bias)[tid];
    *(float4*)xin = v;
    u16 o0 = f2b((xin[0] - mu) * rstd * sc[0] + bi[0]);
    u16 o1 = f2b((xin[1] - mu) * rstd * sc[1] + bi[1]);
    u16 o2 = f2b((xin[2] - mu) * rstd * sc[2] + bi[2]);
    u16 o3 = f2b((xin[3] - mu) * rstd * sc[3] + bi[3]);
    unsigned int u0 = (unsigned int)o0 | ((unsigned int)o1 << 16);
    unsigned int u1 = (unsigned int)o2 | ((unsigned int)o3 << 16);
    uint2 pk = {u0, u1};
    *(uint2*)(out + (size_t)row * EMBED + tid * 4) = pk;
}

// ---------------- all weight transposes in ONE dispatch ----------------
__global__ __launch_bounds__(256) void transpose_all(const float* __restrict__ wq,
                                                     const float* __restrict__ wk,
                                                     const float* __restrict__ wv,
                                                     const float* __restrict__ wo,
                                                     const float* __restrict__ w1,
                                                     const float* __restrict__ w2,
                                                     const float* __restrict__ bq,
                                                     const float* __restrict__ bk,
                                                     const float* __restrict__ bv,
                                                     u16* __restrict__ wqkvT,
                                                     u16* __restrict__ woT,
                                                     u16* __restrict__ w1T,
                                                     u16* __restrict__ w2T,
                                                     float* __restrict__ bias_qkv) {
    __shared__ float Ls[64][65];
    int z = blockIdx.z;
    int bx = blockIdx.x, by = blockIdx.y;
    const float* W;
    u16* WT;
    int K, N;
    if (z < 4) {
        W = (z == 0) ? wq : (z == 1) ? wk : (z == 2) ? wv : wo;
        WT = (z < 3) ? (wqkvT + (size_t)z * 1024 * 1024) : woT;
        K = 1024; N = 1024;
    } else if (z < 8) {
        W = w1; WT = w1T; K = 1024; N = 4096; bx += (z - 4) * 16;
    } else {
        W = w2; WT = w2T; K = 4096; N = 1024; by += (z - 8) * 16;
    }
    int tid = threadIdx.x;
    if (z == 3 && blockIdx.y == 0 && blockIdx.x < 12) {
        int i = blockIdx.x * 256 + tid;
        bias_qkv[i] = (i < 1024) ? bq[i] : (i < 2048) ? bk[i - 1024] : bv[i - 2048];
    }
    int k0 = by * 64, n0 = bx * 64;
#pragma unroll
    for (int p = 0; p < 4; p++) {
        int r = (tid >> 4) + 16 * p, c = (tid & 15) * 4;
        float4 v = *(const float4*)(W + (size_t)(k0 + r) * N + n0 + c);
        Ls[r][c] = v.x; Ls[r][c + 1] = v.y; Ls[r][c + 2] = v.z; Ls[r][c + 3] = v.w;
    }
    __syncthreads();
#pragma unroll
    for (int p = 0; p < 4; p++) {
        int n = (tid >> 4) + 16 * p, k4 = (tid & 15) * 4;
        u16 o0 = f2b(Ls[k4][n]), o1 = f2b(Ls[k4 + 1][n]);
        u16 o2 = f2b(Ls[k4 + 2][n]), o3 = f2b(Ls[k4 + 3][n]);
        unsigned int a = (unsigned int)o0 | ((unsigned int)o1 << 16);
        unsigned int b = (unsigned int)o2 | ((unsigned int)o3 << 16);
        uint2 pk = {a, b};
        *(uint2*)(WT + (size_t)(n0 + n) * K + k0 + k4) = pk;
    }
}

// ======== shared GEMM staging: global_load_lds(16B) + XOR swizzle ========
static __device__ __forceinline__ void stage2(const u16* __restrict__ Ag,
                                              const u16* __restrict__ Wg,
                                              u16* As, u16* Ws,
                                              int w, int l, int K) {
    int r0 = 16 * w + (l >> 3);
    int scol = ((l & 7) ^ (l >> 3)) * 8;
    char* a0 = (char*)As + w * 2048;
    char* w0 = (char*)Ws + w * 2048;
    gl16(Ag + (size_t)r0 * K + scol, a0);
    gl16(Ag + (size_t)(r0 + 8) * K + scol, a0 + 1024);
    gl16(Wg + (size_t)r0 * K + scol, w0);
    gl16(Wg + (size_t)(r0 + 8) * K + scol, w0 + 1024);
}

// ---------------- bf16 MFMA GEMM: C[M,N] = A[M,K] @ WT[N,K]^T ----------------
template <int MODE>
__global__ __launch_bounds__(256) void gemm_bf16(const u16* __restrict__ A,
                                                 const u16* __restrict__ WT,
                                                 const float* __restrict__ bias,
                                                 const float* __restrict__ resid,
                                                 float* __restrict__ outf,
                                                 float* __restrict__ outf2,
                                                 u16* __restrict__ outb, int N, int K) {
    __shared__ u16 As[64 * 64];
    __shared__ u16 Ws[64 * 64];
    int tid = threadIdx.x;
    int m0 = blockIdx.y * 64, n0 = blockIdx.x * 64;
    int w = tid >> 6, l = tid & 63, lr = l & 15, lg = l >> 4;
    f32x4 acc[4] = {};

    const u16* Ag = A + (size_t)m0 * K;
    const u16* Wg = WT + (size_t)n0 * K;

    for (int k0 = 0; k0 < K; k0 += 64) {
        __syncthreads();
        stage2(Ag + k0, Wg + k0, As, Ws, w, l, K);
        __syncthreads();
#pragma unroll
        for (int ks = 0; ks < 2; ks++) {
            int abyte = ((16 * w + lr) * 128 + lg * 16 + ks * 64) ^ ((lr & 7) << 4);
            bf16x8 af = *(bf16x8*)((char*)As + abyte);
#pragma unroll
            for (int f = 0; f < 4; f++) {
                int bbyte = ((16 * f + lr) * 128 + lg * 16 + ks * 64) ^ ((lr & 7) << 4);
                bf16x8 bfr = *(bf16x8*)((char*)Ws + bbyte);
                acc[f] = __builtin_amdgcn_mfma_f32_16x16x32_bf16(af, bfr, acc[f], 0, 0, 0);
            }
        }
    }

    int gr0 = m0 + 16 * w + 4 * lg;
#pragma unroll
    for (int f = 0; f < 4; f++) {
        int gc = n0 + 16 * f + lr;
        float bv = bias[gc];
#pragma unroll
        for (int r = 0; r < 4; r++) {
            int gm = gr0 + r;
            float v = acc[f][r] + bv;
            if (MODE == 3) v = 0.5f * v * (1.0f + erff(v * 0.70710678118654752f));
            if (MODE == 2 || MODE == 4) v += resid[(size_t)gm * EMBED + gc];
            if (MODE == 0 || MODE == 3) {
                outb[(size_t)gm * N + gc] = f2b(v);
            } else if (MODE == 1) {
                int b_ = gm >> 7, t_ = gm & 127, h_ = gc >> 6, d_ = gc & 63;
                outf[(((size_t)(b_ * HEADS + h_)) * SEQA + CARRY + t_) * HDIM + d_] = v;
            } else if (MODE == 5) {
                if (gc < 1024) {
                    outb[(size_t)gm * EMBED + gc] = f2b(v);
                } else {
                    int which = gc >> 10;
                    int gc2 = gc & 1023;
                    int b_ = gm >> 7, t_ = gm & 127, h_ = gc2 >> 6, d_ = gc2 & 63;
                    float* dst = (which == 1) ? outf : outf2;
                    dst[(((size_t)(b_ * HEADS + h_)) * SEQA + CARRY + t_) * HDIM + d_] = v;
                }
            } else {
                outf[(size_t)gm * EMBED + gc] = v;
            }
        }
    }
}

// ---------------- split-K GEMM -> fp32 partials ----------------
__global__ __launch_bounds__(256) void gemm_splitk(const u16* __restrict__ A,
                                                   const u16* __restrict__ WT,
                                                   float* __restrict__ part,
                                                   int N, int Ktot, int Klen) {
    __shared__ u16 As[64 * 64];
    __shared__ u16 Ws[64 * 64];
    int tid = threadIdx.x;
    int m0 = blockIdx.y * 64, n0 = blockIdx.x * 64;
    int k0s = blockIdx.z * Klen;
    int w = tid >> 6, l = tid & 63, lr = l & 15, lg = l >> 4;
    f32x4 acc[4] = {};

    const u16* Ag = A + (size_t)m0 * Ktot;
    const u16* Wg = WT + (size_t)n0 * Ktot;

    for (int k0 = k0s; k0 < k0s + Klen; k0 += 64) {
        __syncthreads();
        stage2(Ag + k0, Wg + k0, As, Ws, w, l, Ktot);
        __syncthreads();
#pragma unroll
        for (int ks = 0; ks < 2; ks++) {
            int abyte = ((16 * w + lr) * 128 + lg * 16 + ks * 64) ^ ((lr & 7) << 4);
            bf16x8 af = *(bf16x8*)((char*)As + abyte);
#pragma unroll
            for (int f = 0; f < 4; f++) {
                int bbyte = ((16 * f + lr) * 128 + lg * 16 + ks * 64) ^ ((lr & 7) << 4);
                bf16x8 bfr = *(bf16x8*)((char*)Ws + bbyte);
                acc[f] = __builtin_amdgcn_mfma_f32_16x16x32_bf16(af, bfr, acc[f], 0, 0, 0);
            }
        }
    }

    float* pbase = part + (size_t)blockIdx.z * MROWS * N;
    int gr0 = m0 + 16 * w + 4 * lg;
#pragma unroll
    for (int f = 0; f < 4; f++) {
        int gc = n0 + 16 * f + lr;
#pragma unroll
        for (int r = 0; r < 4; r++)
            pbase[(size_t)(gr0 + r) * N + gc] = acc[f][r];
    }
}

// ---- combine (final): out = resid + bias + sum_s part[s] ----
template <int NS>
__global__ __launch_bounds__(256) void combine_add(const float* __restrict__ part,
                                                   const float* __restrict__ bias,
                                                   const float* __restrict__ resid,
                                                   float* __restrict__ out) {
    size_t e = ((size_t)blockIdx.x * 256 + threadIdx.x) * 4;
    int n0 = (int)(e & 1023);
    float4 v = *(const float4*)(resid + e);
    float4 b = *(const float4*)(bias + n0);
    v.x += b.x; v.y += b.y; v.z += b.z; v.w += b.w;
#pragma unroll
    for (int s = 0; s < NS; s++) {
        float4 p = *(const float4*)(part + (size_t)s * MROWS * EMBED + e);
        v.x += p.x; v.y += p.y; v.z += p.z; v.w += p.w;
    }
    *(float4*)(out + e) = v;
}

// ---- combine proj + LN2 fused ----
__global__ __launch_bounds__(256) void combine_ln(const float* __restrict__ part,
                                                  const float* __restrict__ bias,
                                                  const float* __restrict__ resid,
                                                  const float* __restrict__ ln_s,
                                                  const float* __restrict__ ln_b,
                                                  float* __restrict__ out,
                                                  u16* __restrict__ outb) {
    int row = blockIdx.x, tid = threadIdx.x;
    size_t base = (size_t)row * EMBED + tid * 4;
    float4 v = *(const float4*)(resid + base);
    float4 b = *(const float4*)(bias + tid * 4);
    v.x += b.x; v.y += b.y; v.z += b.z; v.w += b.w;
#pragma unroll
    for (int s = 0; s < 2; s++) {
        float4 p = *(const float4*)(part + (size_t)s * MROWS * EMBED + base);
        v.x += p.x; v.y += p.y; v.z += p.z; v.w += p.w;
    }
    *(float4*)(out + base) = v;

    float s1 = v.x + v.y + v.z + v.w;
    float s2 = v.x * v.x + v.y * v.y + v.z * v.z + v.w * v.w;
    for (int o = 32; o > 0; o >>= 1) {
        s1 += __shfl_down(s1, o, 64);
        s2 += __shfl_down(s2, o, 64);
    }
    __shared__ float ls[8], ls2[8];
    int wid = tid >> 6, lane = tid & 63;
    if (lane == 0) { ls[wid] = s1; ls2[wid] = s2; }
    __syncthreads();
    if (tid == 0) {
        float S = 0.f, S2 = 0.f;
        for (int i = 0; i < 4; i++) { S += ls[i]; S2 += ls2[i]; }
        float mu = S * (1.0f / EMBED);
        float var = S2 * (1.0f / EMBED) - mu * mu;
        ls[0] = mu;
        ls2[0] = rsqrtf(var + 1e-5f);
    }
    __syncthreads();
    float mu = ls[0], rstd = ls2[0];
    float sc[4], bi[4];
    *(float4*)sc = ((const float4*)ln_s)[tid];
    *(float4*)bi = ((const float4*)ln_b)[tid];
    u16 o0 = f2b((v.x - mu) * rstd * sc[0] + bi[0]);
    u16 o1 = f2b((v.y - mu) * rstd * sc[1] + bi[1]);
    u16 o2 = f2b((v.z - mu) * rstd * sc[2] + bi[2]);
    u16 o3 = f2b((v.w - mu) * rstd * sc[3] + bi[3]);
    unsigned int u0 = (unsigned int)o0 | ((unsigned int)o1 << 16);
    unsigned int u1 = (unsigned int)o2 | ((unsigned int)o3 << 16);
    uint2 pk = {u0, u1};
    *(uint2*)(outb + base) = pk;
}

// ---------------- MFMA flash attention v5: 512 threads / 8 waves per block,
// one block = (bh, kv-split) x ALL 128 q-rows (wave w owns rows 16w..16w+15).
// Carry read ONCE globally + written through once. Light register prefetch
// (K: 2 float4, V: 8 dwords column-per-lane), raw barriers (no vmcnt drain).
__global__ __launch_bounds__(512, 4) void attn_mfma_split(const u16* __restrict__ qb,
                                                          const float* __restrict__ kc,
                                                          const float* __restrict__ vc,
                                                          float* __restrict__ k_all,
                                                          float* __restrict__ v_all,
                                                          float* __restrict__ part_acc,
                                                          float* __restrict__ part_m,
                                                          float* __restrict__ part_l) {
    __shared__ u16 Ks[64 * 64];   // [s][d] bf16, swizzled
    __shared__ u16 Vt[64 * 64];   // [d][s] bf16, swizzled
    __shared__ u16 Ps[128 * 64];  // [t][s] bf16, swizzled

    int bh = blockIdx.x, b = bh >> 4, h = bh & 15;
    int sp = blockIdx.y;
    int tid = threadIdx.x;
    int w = tid >> 6, l = tid & 63, lr = l & 15, lg = l >> 4;

    // Q fragment: wave w owns q-rows [16w, 16w+16)
    bf16x8 qf0, qf1;
    {
        const u16* qrow = qb + (size_t)(b * TLEN + 16 * w + lr) * EMBED + h * HDIM;
        qf0 = *(const bf16x8*)(qrow + 8 * lg);
        qf1 = *(const bf16x8*)(qrow + 8 * lg + 32);
    }

    const float* kcb = kc + (size_t)bh * CARRY * HDIM;
    const float* vcb = vc + (size_t)bh * CARRY * HDIM;
    const float* kb = k_all + (size_t)bh * SEQA * HDIM;
    const float* vb = v_all + (size_t)bh * SEQA * HDIM;
    float* kwr = k_all + (size_t)bh * SEQA * HDIM;
    float* vwr = v_all + (size_t)bh * SEQA * HDIM;

    float m_run[4], l_run[4];
    f32x4 oacc[4] = {};
#pragma unroll
    for (int r = 0; r < 4; r++) { m_run[r] = -1e30f; l_run[r] = 0.f; }

    const int nt = SEQA / 64;                   // 66
    const int tps = (nt + NSPLIT - 1) / NSPLIT; // 9
    int kt0 = sp * tps;
    int kt1 = min(kt0 + tps, nt);

    // staging geometry (512 threads)
    int krow = tid >> 3;        // 0..63 K rows (wave w: rows 8w..8w+8)
    int kcol = (tid & 7) * 8;   // 8 fp32 cols per thread
    int vs0 = 8 * w;            // V s-base for this wave; lane covers column d = l

    float4 kA[2], kB[2];
    float vA[8], vB[8];

    // prologue: load first tile into A
    {
        bool cn = kt0 < 64;
        const float* ksrc = cn ? kcb : kb;
        const float* vsrc = cn ? vcb : vb;
        kA[0] = *(const float4*)(ksrc + (size_t)(kt0 * 64 + krow) * HDIM + kcol);
        kA[1] = *(const float4*)(ksrc + (size_t)(kt0 * 64 + krow) * HDIM + kcol + 4);
#pragma unroll
        for (int q = 0; q < 8; q++)
            vA[q] = vsrc[(size_t)(kt0 * 64 + vs0 + q) * HDIM + l];
    }

    auto body = [&](float4 (&kc_)[2], float (&vc_)[8],
                    float4 (&kn_)[2], float (&vn_)[8], int kt) {
        bool carry_t = kt < 64;
        int ktn = kt + 1;
        if (ktn < kt1) {
            bool cn = ktn < 64;
            const float* ksrc = cn ? kcb : kb;
            const float* vsrc = cn ? vcb : vb;
            kn_[0] = *(const float4*)(ksrc + (size_t)(ktn * 64 + krow) * HDIM + kcol);
            kn_[1] = *(const float4*)(ksrc + (size_t)(ktn * 64 + krow) * HDIM + kcol + 4);
#pragma unroll
            for (int q = 0; q < 8; q++)
                vn_[q] = vsrc[(size_t)(ktn * 64 + vs0 + q) * HDIM + l];
        }
        // carry write-through: this block exclusively owns its kv slice
        if (carry_t) {
            *(float4*)(kwr + (size_t)(kt * 64 + krow) * HDIM + kcol) = kc_[0];
            *(float4*)(kwr + (size_t)(kt * 64 + krow) * HDIM + kcol + 4) = kc_[1];
#pragma unroll
            for (int q = 0; q < 8; q++)
                vwr[(size_t)(kt * 64 + vs0 + q) * HDIM + l] = vc_[q];
        }
        bar_plain(); // previous tile's PV reads of Ks/Vt done
        // K -> LDS: one bf16x8 per thread
        {
            u16 t[8];
            const float* kf = (const float*)&kc_[0];
#pragma unroll
            for (int j = 0; j < 8; j++) t[j] = f2b(kf[j]);
            *(bf16x8*)((char*)Ks + ((krow * 128 + kcol * 2) ^ ((krow & 7) << 4))) =
                *(bf16x8*)t;
        }
        // V -> LDS transposed: column-per-lane, one bf16x8 per thread
        {
            u16 t[8];
#pragma unroll
            for (int q = 0; q < 8; q++) t[q] = f2b(vc_[q]);
            *(bf16x8*)((char*)Vt + ((l * 128 + vs0 * 2) ^ ((l & 7) << 4))) =
                *(bf16x8*)t;
        }
        bar_lgkm(); // staging visible (vmcnt NOT drained)

        // ==== compute (per wave: 16 q-rows) ====
        float x[4][4];
#pragma unroll
        for (int f = 0; f < 4; f++) {
            int row = 16 * f + lr;
            int swz = (row & 7) << 4;
            bf16x8 kf0 = *(bf16x8*)((char*)Ks + ((row * 128 + 16 * lg) ^ swz));
            bf16x8 kf1 = *(bf16x8*)((char*)Ks + ((row * 128 + 16 * lg + 64) ^ swz));
            f32x4 z = {};
            z = __builtin_amdgcn_mfma_f32_16x16x32_bf16(qf0, kf0, z, 0, 0, 0);
            z = __builtin_amdgcn_mfma_f32_16x16x32_bf16(qf1, kf1, z, 0, 0, 0);
#pragma unroll
            for (int r = 0; r < 4; r++) x[f][r] = z[r] * 0.125f;
        }
        if (kt * 64 + 63 > CARRY + 16 * w) {
#pragma unroll
            for (int f = 0; f < 4; f++) {
                int sg = kt * 64 + 16 * f + lr;
#pragma unroll
                for (int r = 0; r < 4; r++) {
                    int tg = 16 * w + 4 * lg + r;
                    if (sg > CARRY + tg) x[f][r] = -1e30f;
                }
            }
        }
#pragma unroll
        for (int r = 0; r < 4; r++) {
            float mt = fmaxf(fmaxf(x[0][r], x[1][r]), fmaxf(x[2][r], x[3][r]));
            mt = fmaxf(mt, __shfl_xor(mt, 1, 64));
            mt = fmaxf(mt, __shfl_xor(mt, 2, 64));
            mt = fmaxf(mt, __shfl_xor(mt, 4, 64));
            mt = fmaxf(mt, __shfl_xor(mt, 8, 64));
            float mn = fmaxf(m_run[r], mt);
            float fs = __expf(m_run[r] - mn);
            m_run[r] = mn;
            float s = 0.f;
#pragma unroll
            for (int f = 0; f < 4; f++) {
                float p = __expf(x[f][r] - mn);
                x[f][r] = p;
                s += p;
            }
            s += __shfl_xor(s, 1, 64);
            s += __shfl_xor(s, 2, 64);
            s += __shfl_xor(s, 4, 64);
            s += __shfl_xor(s, 8, 64);
            l_run[r] = l_run[r] * fs + s;
#pragma unroll
            for (int f2 = 0; f2 < 4; f2++) oacc[f2][r] *= fs;
        }
#pragma unroll
        for (int f = 0; f < 4; f++) {
#pragma unroll
            for (int r = 0; r < 4; r++) {
                int row = 16 * w + 4 * lg + r;
                int byte = (row * 128 + (16 * f + lr) * 2) ^ ((row & 7) << 4);
                *(u16*)((char*)Ps + byte) = f2b(x[f][r]);
            }
        }
        // PV (Ps rows are wave-local; compiler inserts lgkm waits)
        {
            int prow = 16 * w + lr;
            int pswz = (prow & 7) << 4;
            bf16x8 pa0 = *(bf16x8*)((char*)Ps + ((prow * 128 + 16 * lg) ^ pswz));
            bf16x8 pa1 = *(bf16x8*)((char*)Ps + ((prow * 128 + 16 * lg + 64) ^ pswz));
#pragma unroll
            for (int f2 = 0; f2 < 4; f2++) {
                int d = 16 * f2 + lr;
                int vswz = (d & 7) << 4;
                bf16x8 vf0 = *(bf16x8*)((char*)Vt + ((d * 128 + 16 * lg) ^ vswz));
                bf16x8 vf1 = *(bf16x8*)((char*)Vt + ((d * 128 + 16 * lg + 64) ^ vswz));
                oacc[f2] = __builtin_amdgcn_mfma_f32_16x16x32_bf16(pa0, vf0, oacc[f2], 0, 0, 0);
                oacc[f2] = __builtin_amdgcn_mfma_f32_16x16x32_bf16(pa1, vf1, oacc[f2], 0, 0, 0);
            }
        }
    };

    for (int kt = kt0; kt < kt1; kt += 2) {
        body(kA, vA, kB, vB, kt);
        if (kt + 1 < kt1) body(kB, vB, kA, vA, kt + 1);
    }

    int p = bh * NSPLIT + sp;
    if (lr == 0) {
#pragma unroll
        for (int r = 0; r < 4; r++) {
            int row = 16 * w + 4 * lg + r;
            part_m[(size_t)p * 128 + row] = m_run[r];
            part_l[(size_t)p * 128 + row] = l_run[r];
        }
    }
#pragma unroll
    for (int f2 = 0; f2 < 4; f2++) {
#pragma unroll
        for (int r = 0; r < 4; r++) {
            int row = 16 * w + 4 * lg + r;
            part_acc[(size_t)p * 8192 + row * 64 + 16 * f2 + lr] = oacc[f2][r];
        }
    }
}

// ---- attn combine: merge NSPLIT kv-splits -> ctx bf16 ----
__global__ __launch_bounds__(256) void attn_combine(const float* __restrict__ part_acc,
                                                    const float* __restrict__ part_m,
                                                    const float* __restrict__ part_l,
                                                    u16* __restrict__ ctx) {
    int g = blockIdx.x;                 // 256 blocks: bh*2 + qh
    int bh = g >> 1, qh = g & 1, b = bh >> 4, h = bh & 15;
    int t = threadIdx.x;
    int r = t >> 2, c0 = (t & 3) * 16;
    int row = qh * 64 + r;
    int p0 = bh * NSPLIT;

    float ms[NSPLIT];
    float M = -1e30f;
#pragma unroll
    for (int s = 0; s < NSPLIT; s++) {
        ms[s] = part_m[(size_t)(p0 + s) * 128 + row];
        M = fmaxf(M, ms[s]);
    }
    float wgt[NSPLIT];
    float L = 0.f;
#pragma unroll
    for (int s = 0; s < NSPLIT; s++) {
        wgt[s] = __expf(ms[s] - M);
        L += wgt[s] * part_l[(size_t)(p0 + s) * 128 + row];
    }
    float inv = 1.0f / L;

    size_t grow = (size_t)(b * TLEN + row) * EMBED + h * HDIM + c0;
#pragma unroll
    for (int j = 0; j < 16; j += 4) {
        float4 a = {0.f, 0.f, 0.f, 0.f};
#pragma unroll
        for (int s = 0; s < NSPLIT; s++) {
            float4 p = *(const float4*)(part_acc + (size_t)(p0 + s) * 8192 + row * 64 + c0 + j);
            a.x += wgt[s] * p.x; a.y += wgt[s] * p.y; a.z += wgt[s] * p.z; a.w += wgt[s] * p.w;
        }
        u16 o0 = f2b(a.x * inv), o1 = f2b(a.y * inv), o2 = f2b(a.z * inv), o3 = f2b(a.w * inv);
        unsigned int u0 = (unsigned int)o0 | ((unsigned int)o1 << 16);
        unsigned int u1 = (unsigned int)o2 | ((unsigned int)o3 << 16);
        uint2 pk = {u0, u1};
        *(uint2*)(ctx + grow + j) = pk;
    }
}

// ---------------- fallback non-split attention (reads k_all/v_all) ----------------
__global__ __launch_bounds__(256) void attn_mfma(const u16* __restrict__ qb,
                                                 const float* __restrict__ k_all,
                                                 const float* __restrict__ v_all,
                                                 u16* __restrict__ ctx) {
    __shared__ u16 Ks[64 * 64];
    __shared__ u16 Vt[64 * 64];
    __shared__ u16 Ps[64 * 64];

    int bh = blockIdx.x, b = bh >> 4, h = bh & 15;
    int q0 = blockIdx.y * 64;
    int tid = threadIdx.x;
    int w = tid >> 6, l = tid & 63, lr = l & 15, lg = l >> 4;

    bf16x8 qf0, qf1;
    {
        const u16* qrow = qb + (size_t)(b * TLEN + q0 + 16 * w + lr) * EMBED + h * HDIM;
        qf0 = *(const bf16x8*)(qrow + 8 * lg);
        qf1 = *(const bf16x8*)(qrow + 8 * lg + 32);
    }
    const float* kb = k_all + (size_t)bh * SEQA * HDIM;
    const float* vb = v_all + (size_t)bh * SEQA * HDIM;

    float m_run[4], l_run[4];
    f32x4 oacc[4] = {};
#pragma unroll
    for (int r = 0; r < 4; r++) { m_run[r] = -1e30f; l_run[r] = 0.f; }

    int nt = (CARRY + q0 + 64) >> 6;
    for (int kt = 0; kt < nt; kt++) {
        __syncthreads();
#pragma unroll
        for (int p = 0; p < 4; p++) {
            int s = (tid >> 4) + 16 * p, c = (tid & 15) * 4;
            float4 kv = *(const float4*)(kb + (size_t)(kt * 64 + s) * HDIM + c);
            u16 t0 = f2b(kv.x), t1 = f2b(kv.y), t2 = f2b(kv.z), t3 = f2b(kv.w);
            unsigned int a = (unsigned int)t0 | ((unsigned int)t1 << 16);
            unsigned int bq = (unsigned int)t2 | ((unsigned int)t3 << 16);
            uint2 pk = {a, bq};
            int byte = (s * 128 + c * 2) ^ ((s & 7) << 4);
            *(uint2*)((char*)Ks + byte) = pk;
        }
        {
            int d = tid & 63;
            u16 tmp[16];
#pragma unroll
            for (int q = 0; q < 16; q++)
                tmp[q] = f2b(vb[(size_t)(kt * 64 + 16 * w + q) * HDIM + d]);
            int b0 = (d * 128 + 32 * w) ^ ((d & 7) << 4);
            int b1 = (d * 128 + 32 * w + 16) ^ ((d & 7) << 4);
            *(bf16x8*)((char*)Vt + b0) = *(bf16x8*)&tmp[0];
            *(bf16x8*)((char*)Vt + b1) = *(bf16x8*)&tmp[8];
        }
        __syncthreads();

        float x[4][4];
#pragma unroll
        for (int f = 0; f < 4; f++) {
            int row = 16 * f + lr;
            int swz = (row & 7) << 4;
            bf16x8 kf0 = *(bf16x8*)((char*)Ks + ((row * 128 + 16 * lg) ^ swz));
            bf16x8 kf1 = *(bf16x8*)((char*)Ks + ((row * 128 + 16 * lg + 64) ^ swz));
            f32x4 z = {};
            z = __builtin_amdgcn_mfma_f32_16x16x32_bf16(qf0, kf0, z, 0, 0, 0);
            z = __builtin_amdgcn_mfma_f32_16x16x32_bf16(qf1, kf1, z, 0, 0, 0);
#pragma unroll
            for (int r = 0; r < 4; r++) x[f][r] = z[r] * 0.125f;
        }
        if (kt * 64 + 63 > CARRY + q0 + 16 * w) {
#pragma unroll
            for (int f = 0; f < 4; f++) {
                int sg = kt * 64 + 16 * f + lr;
#pragma unroll
                for (int r = 0; r < 4; r++) {
                    int tg = q0 + 16 * w + 4 * lg + r;
                    if (sg > CARRY + tg) x[f][r] = -1e30f;
                }
            }
        }
#pragma unroll
        for (int r = 0; r < 4; r++) {
            float mt = fmaxf(fmaxf(x[0][r], x[1][r]), fmaxf(x[2][r], x[3][r]));
            mt = fmaxf(mt, __shfl_xor(mt, 1, 64));
            mt = fmaxf(mt, __shfl_xor(mt, 2, 64));
            mt = fmaxf(mt, __shfl_xor(mt, 4, 64));
            mt = fmaxf(mt, __shfl_xor(mt, 8, 64));
            float mn = fmaxf(m_run[r], mt);
            float fs = __expf(m_run[r] - mn);
            m_run[r] = mn;
            float s = 0.f;
#pragma unroll
            for (int f = 0; f < 4; f++) {
                float p = __expf(x[f][r] - mn);
                x[f][r] = p;
                s += p;
            }
            s += __shfl_xor(s, 1, 64);
            s += __shfl_xor(s, 2, 64);
            s += __shfl_xor(s, 4, 64);
            s += __shfl_xor(s, 8, 64);
            l_run[r] = l_run[r] * fs + s;
#pragma unroll
            for (int f2 = 0; f2 < 4; f2++) oacc[f2][r] *= fs;
        }
#pragma unroll
        for (int f = 0; f < 4; f++) {
#pragma unroll
            for (int r = 0; r < 4; r++) {
                int row = 16 * w + 4 * lg + r;
                int byte = (row * 128 + (16 * f + lr) * 2) ^ ((row & 7) << 4);
                *(u16*)((char*)Ps + byte) = f2b(x[f][r]);
            }
        }
        {
            int prow = 16 * w + lr;
            int pswz = (prow & 7) << 4;
            bf16x8 pa0 = *(bf16x8*)((char*)Ps + ((prow * 128 + 16 * lg) ^ pswz));
            bf16x8 pa1 = *(bf16x8*)((char*)Ps + ((prow * 128 + 16 * lg + 64) ^ pswz));
#pragma unroll
            for (int f2 = 0; f2 < 4; f2++) {
                int d = 16 * f2 + lr;
                int vswz = (d & 7) << 4;
                bf16x8 vf0 = *(bf16x8*)((char*)Vt + ((d * 128 + 16 * lg) ^ vswz));
                bf16x8 vf1 = *(bf16x8*)((char*)Vt + ((d * 128 + 16 * lg + 64) ^ vswz));
                oacc[f2] = __builtin_amdgcn_mfma_f32_16x16x32_bf16(pa0, vf0, oacc[f2], 0, 0, 0);
                oacc[f2] = __builtin_amdgcn_mfma_f32_16x16x32_bf16(pa1, vf1, oacc[f2], 0, 0, 0);
            }
        }
    }
#pragma unroll
    for (int r = 0; r < 4; r++) {
        float inv = 1.0f / l_run[r];
        size_t grow = (size_t)(b * TLEN + q0 + 16 * w + 4 * lg + r) * EMBED + h * HDIM;
#pragma unroll
        for (int f2 = 0; f2 < 4; f2++)
            ctx[grow + 16 * f2 + lr] = f2b(oacc[f2][r] * inv);
    }
}

extern "C" void kernel_launch(void* const* d_in, const int* in_sizes, int n_in,
                              void* d_out, int out_size, void* d_ws, size_t ws_size,
                              hipStream_t stream) {
    const float* hidden = (const float*)d_in[0];
    const float* key_carry = (const float*)d_in[1];
    const float* value_carry = (const float*)d_in[2];
    const float* ln1_s = (const float*)d_in[3];
    const float* ln1_b = (const float*)d_in[4];
    const float* wq = (const float*)d_in[5];
    const float* bq = (const float*)d_in[6];
    const float* wk = (const float*)d_in[7];
    const float* bk = (const float*)d_in[8];
    const float* wv = (const float*)d_in[9];
    const float* bv = (const float*)d_in[10];
    const float* wo = (const float*)d_in[11];
    const float* bo = (const float*)d_in[12];
    const float* ln2_s = (const float*)d_in[13];
    const float* ln2_b = (const float*)d_in[14];
    const float* w1 = (const float*)d_in[15];
    const float* b1 = (const float*)d_in[16];
    const float* w2 = (const float*)d_in[17];
    const float* b2 = (const float*)d_in[18];

    float* out_hidden = (float*)d_out;
    float* k_all = out_hidden + (size_t)MROWS * EMBED;
    float* v_all = k_all + (size_t)BATCH * HEADS * SEQA * HDIM;

    u16* wsu = (u16*)d_ws;
    u16* wqkvT = wsu;                  // [3072][1024]
    u16* woT = wsu + 3145728;          // [1024][1024]
    u16* w1T = wsu + 4194304;          // [4096][1024]
    u16* w2T = wsu + 8388608;          // [1024][4096]
    u16* xb  = wsu + 12582912;
    u16* qbb = wsu + 13631488;
    u16* ctxb = wsu + 14680064;
    u16* fb  = wsu + 15728640;
    u16* h1b = wsu + 16777216;         // [1024][4096]
    float* bias_qkv = (float*)(wsu + 20971520);          // 3072 f32
    float* part = (float*)(wsu + 20977664);
    const size_t nparts = (size_t)128 * NSPLIT;          // bh x splits
    const size_t need = (size_t)20977664 * 2 +
                        (nparts * 8192 + 2 * nparts * 128) * 4;

    transpose_all<<<dim3(16, 16, 12), 256, 0, stream>>>(wq, wk, wv, wo, w1, w2, bq, bk, bv,
                                                        wqkvT, woT, w1T, w2T, bias_qkv);

    ln_kernel<<<MROWS, 256, 0, stream>>>(hidden, ln1_s, ln1_b, xb);

    if (ws_size >= need) {
        // fused QKV: Q->qbb bf16, K/V -> k_all/v_all new rows (4096..4223)
        gemm_bf16<5><<<dim3(48, 16), 256, 0, stream>>>(xb, wqkvT, bias_qkv, nullptr,
                                                       k_all, v_all, qbb, 3072, EMBED);
        float* part_acc = part;
        float* part_m = part + nparts * 8192;
        float* part_l = part_m + nparts * 128;
        attn_mfma_split<<<dim3(BATCH * HEADS, NSPLIT), 512, 0, stream>>>(
            qbb, key_carry, value_carry, k_all, v_all, part_acc, part_m, part_l);
        attn_combine<<<256, 256, 0, stream>>>(part_acc, part_m, part_l, ctxb);

        gemm_splitk<<<dim3(16, 16, 2), 256, 0, stream>>>(ctxb, woT, part, EMBED, EMBED, 512);
        combine_ln<<<1024, 256, 0, stream>>>(part, bo, hidden, ln2_s, ln2_b, out_hidden, fb);

        gemm_bf16<3><<<dim3(64, 16), 256, 0, stream>>>(fb, w1T, b1, nullptr, nullptr, nullptr,
                                                       h1b, FFDIM, EMBED);
        gemm_splitk<<<dim3(16, 16, 4), 256, 0, stream>>>(h1b, w2T, part, EMBED, FFDIM, 1024);
        combine_add<4><<<1024, 256, 0, stream>>>(part, b2, out_hidden, out_hidden);
    } else {
        // fallback: non-split schedule with explicit carry copy
        copy_carry_kernel<<<2048, 256, 0, stream>>>(
            (const float4*)key_carry, (const float4*)value_carry,
            (float4*)k_all, (float4*)v_all);
        u16* wqT = wqkvT;
        u16* wkT = wqkvT + 1048576;
        u16* wvT = wqkvT + 2097152;
        gemm_bf16<0><<<dim3(16, 16), 256, 0, stream>>>(xb, wqT, bq, nullptr, nullptr, nullptr,
                                                       qbb, EMBED, EMBED);
        gemm_bf16<1><<<dim3(16, 16), 256, 0, stream>>>(xb, wkT, bk, nullptr, k_all, nullptr,
                                                       nullptr, EMBED, EMBED);
        gemm_bf16<1><<<dim3(16, 16), 256, 0, stream>>>(xb, wvT, bv, nullptr, v_all, nullptr,
                                                       nullptr, EMBED, EMBED);
        attn_mfma<<<dim3(BATCH * HEADS, 2), 256, 0, stream>>>(qbb, k_all, v_all, ctxb);
        gemm_bf16<2><<<dim3(16, 16), 256, 0, stream>>>(ctxb, woT, bo, hidden, out_hidden,
                                                       nullptr, nullptr, EMBED, EMBED);
        ln_kernel<<<MROWS, 256, 0, stream>>>(out_hidden, ln2_s, ln2_b, fb);
        gemm_bf16<3><<<dim3(64, 16), 256, 0, stream>>>(fb, w1T, b1, nullptr, nullptr, nullptr,
                                                       h1b, FFDIM, EMBED);
        gemm_bf16<4><<<dim3(16, 16), 256, 0, stream>>>(h1b, w2T, b2, out_hidden, out_hidden,
                                                       nullptr, nullptr, EMBED, FFDIM);
    }
}

// Round 8
// 257.597 us; speedup vs baseline: 1.2297x; 1.2297x over previous
//
#include <hip/hip_runtime.h>
#include <hip/hip_bf16.h>
#include <math.h>

#define EMBED 1024
#define HEADS 16
#define HDIM 64
#define FFDIM 4096
#define BATCH 8
#define TLEN 128
#define CARRY 4096
#define SEQA (CARRY + TLEN)   // 4224
#define MROWS (BATCH * TLEN)  // 1024
#define NSPLIT 8

typedef __attribute__((ext_vector_type(8))) short bf16x8;
typedef __attribute__((ext_vector_type(4))) float f32x4;
typedef unsigned short u16;

static __device__ __forceinline__ u16 f2b(float v) {
    __hip_bfloat16 h = __float2bfloat16(v);
    return *reinterpret_cast<u16*>(&h);
}

typedef const __attribute__((address_space(1))) unsigned int g_u32;
typedef __attribute__((address_space(3))) unsigned int l_u32;
static __device__ __forceinline__ void gl16(const void* g, void* l) {
    __builtin_amdgcn_global_load_lds((g_u32*)g, (l_u32*)l, 16, 0, 0);
}

// barrier that does NOT drain vmcnt (stores/prefetch loads stay in flight)
static __device__ __forceinline__ void bar_lgkm() {
    asm volatile("s_waitcnt lgkmcnt(0)" ::: "memory");
    __builtin_amdgcn_s_barrier();
    __builtin_amdgcn_sched_barrier(0);
}
static __device__ __forceinline__ void bar_plain() {
    __builtin_amdgcn_sched_barrier(0);
    __builtin_amdgcn_s_barrier();
}

// ---------------- carry copy (fallback path only) ----------------
__global__ void copy_carry_kernel(const float4* __restrict__ kc, const float4* __restrict__ vc,
                                  float4* __restrict__ k_all, float4* __restrict__ v_all) {
    const size_t total = (size_t)BATCH * HEADS * CARRY * HDIM / 4;
    const size_t DH = (size_t)SEQA * HDIM / 4;
    for (size_t e = (size_t)blockIdx.x * blockDim.x + threadIdx.x; e < total;
         e += (size_t)gridDim.x * blockDim.x) {
        size_t bh = e >> 16;
        size_t rem = e & 65535;
        size_t d = bh * DH + rem;
        k_all[d] = kc[e];
        v_all[d] = vc[e];
    }
}

// ---------------- LayerNorm fp32 in -> bf16 out ----------------
__global__ __launch_bounds__(256) void ln_kernel(const float* __restrict__ in,
                                                 const float* __restrict__ scale,
                                                 const float* __restrict__ bias,
                                                 u16* __restrict__ out) {
    int row = blockIdx.x;
    int tid = threadIdx.x;
    const float4* rin = (const float4*)(in + (size_t)row * EMBED);
    float4 v = rin[tid];
    float s = v.x + v.y + v.z + v.w;
    float s2 = v.x * v.x + v.y * v.y + v.z * v.z + v.w * v.w;
    for (int o = 32; o > 0; o >>= 1) {
        s += __shfl_down(s, o, 64);
        s2 += __shfl_down(s2, o, 64);
    }
    __shared__ float ls[8], ls2[8];
    int wid = tid >> 6, lane = tid & 63;
    if (lane == 0) { ls[wid] = s; ls2[wid] = s2; }
    __syncthreads();
    if (tid == 0) {
        float S = 0.f, S2 = 0.f;
        for (int i = 0; i < 4; i++) { S += ls[i]; S2 += ls2[i]; }
        float mu = S * (1.0f / EMBED);
        float var = S2 * (1.0f / EMBED) - mu * mu;
        ls[0] = mu;
        ls2[0] = rsqrtf(var + 1e-5f);
    }
    __syncthreads();
    float mu = ls[0], rstd = ls2[0];
    float sc[4], bi[4], xin[4];
    *(float4*)sc = ((const float4*)scale)[tid];
    *(float4*)bi = ((const float4*)bias)[tid];
    *(float4*)xin = v;
    u16 o0 = f2b((xin[0] - mu) * rstd * sc[0] + bi[0]);
    u16 o1 = f2b((xin[1] - mu) * rstd * sc[1] + bi[1]);
    u16 o2 = f2b((xin[2] - mu) * rstd * sc[2] + bi[2]);
    u16 o3 = f2b((xin[3] - mu) * rstd * sc[3] + bi[3]);
    unsigned int u0 = (unsigned int)o0 | ((unsigned int)o1 << 16);
    unsigned int u1 = (unsigned int)o2 | ((unsigned int)o3 << 16);
    uint2 pk = {u0, u1};
    *(uint2*)(out + (size_t)row * EMBED + tid * 4) = pk;
}

// ---------------- all weight transposes in ONE dispatch ----------------
__global__ __launch_bounds__(256) void transpose_all(const float* __restrict__ wq,
                                                     const float* __restrict__ wk,
                                                     const float* __restrict__ wv,
                                                     const float* __restrict__ wo,
                                                     const float* __restrict__ w1,
                                                     const float* __restrict__ w2,
                                                     const float* __restrict__ bq,
                                                     const float* __restrict__ bk,
                                                     const float* __restrict__ bv,
                                                     u16* __restrict__ wqkvT,
                                                     u16* __restrict__ woT,
                                                     u16* __restrict__ w1T,
                                                     u16* __restrict__ w2T,
                                                     float* __restrict__ bias_qkv) {
    __shared__ float Ls[64][65];
    int z = blockIdx.z;
    int bx = blockIdx.x, by = blockIdx.y;
    const float* W;
    u16* WT;
    int K, N;
    if (z < 4) {
        W = (z == 0) ? wq : (z == 1) ? wk : (z == 2) ? wv : wo;
        WT = (z < 3) ? (wqkvT + (size_t)z * 1024 * 1024) : woT;
        K = 1024; N = 1024;
    } else if (z < 8) {
        W = w1; WT = w1T; K = 1024; N = 4096; bx += (z - 4) * 16;
    } else {
        W = w2; WT = w2T; K = 4096; N = 1024; by += (z - 8) * 16;
    }
    int tid = threadIdx.x;
    if (z == 3 && blockIdx.y == 0 && blockIdx.x < 12) {
        int i = blockIdx.x * 256 + tid;
        bias_qkv[i] = (i < 1024) ? bq[i] : (i < 2048) ? bk[i - 1024] : bv[i - 2048];
    }
    int k0 = by * 64, n0 = bx * 64;
#pragma unroll
    for (int p = 0; p < 4; p++) {
        int r = (tid >> 4) + 16 * p, c = (tid & 15) * 4;
        float4 v = *(const float4*)(W + (size_t)(k0 + r) * N + n0 + c);
        Ls[r][c] = v.x; Ls[r][c + 1] = v.y; Ls[r][c + 2] = v.z; Ls[r][c + 3] = v.w;
    }
    __syncthreads();
#pragma unroll
    for (int p = 0; p < 4; p++) {
        int n = (tid >> 4) + 16 * p, k4 = (tid & 15) * 4;
        u16 o0 = f2b(Ls[k4][n]), o1 = f2b(Ls[k4 + 1][n]);
        u16 o2 = f2b(Ls[k4 + 2][n]), o3 = f2b(Ls[k4 + 3][n]);
        unsigned int a = (unsigned int)o0 | ((unsigned int)o1 << 16);
        unsigned int b = (unsigned int)o2 | ((unsigned int)o3 << 16);
        uint2 pk = {a, b};
        *(uint2*)(WT + (size_t)(n0 + n) * K + k0 + k4) = pk;
    }
}

// ======== shared GEMM staging: global_load_lds(16B) + XOR swizzle ========
static __device__ __forceinline__ void stage2(const u16* __restrict__ Ag,
                                              const u16* __restrict__ Wg,
                                              u16* As, u16* Ws,
                                              int w, int l, int K) {
    int r0 = 16 * w + (l >> 3);
    int scol = ((l & 7) ^ (l >> 3)) * 8;
    char* a0 = (char*)As + w * 2048;
    char* w0 = (char*)Ws + w * 2048;
    gl16(Ag + (size_t)r0 * K + scol, a0);
    gl16(Ag + (size_t)(r0 + 8) * K + scol, a0 + 1024);
    gl16(Wg + (size_t)r0 * K + scol, w0);
    gl16(Wg + (size_t)(r0 + 8) * K + scol, w0 + 1024);
}

// ---------------- bf16 MFMA GEMM: C[M,N] = A[M,K] @ WT[N,K]^T ----------------
template <int MODE>
__global__ __launch_bounds__(256) void gemm_bf16(const u16* __restrict__ A,
                                                 const u16* __restrict__ WT,
                                                 const float* __restrict__ bias,
                                                 const float* __restrict__ resid,
                                                 float* __restrict__ outf,
                                                 float* __restrict__ outf2,
                                                 u16* __restrict__ outb, int N, int K) {
    __shared__ u16 As[64 * 64];
    __shared__ u16 Ws[64 * 64];
    int tid = threadIdx.x;
    int m0 = blockIdx.y * 64, n0 = blockIdx.x * 64;
    int w = tid >> 6, l = tid & 63, lr = l & 15, lg = l >> 4;
    f32x4 acc[4] = {};

    const u16* Ag = A + (size_t)m0 * K;
    const u16* Wg = WT + (size_t)n0 * K;

    for (int k0 = 0; k0 < K; k0 += 64) {
        __syncthreads();
        stage2(Ag + k0, Wg + k0, As, Ws, w, l, K);
        __syncthreads();
#pragma unroll
        for (int ks = 0; ks < 2; ks++) {
            int abyte = ((16 * w + lr) * 128 + lg * 16 + ks * 64) ^ ((lr & 7) << 4);
            bf16x8 af = *(bf16x8*)((char*)As + abyte);
#pragma unroll
            for (int f = 0; f < 4; f++) {
                int bbyte = ((16 * f + lr) * 128 + lg * 16 + ks * 64) ^ ((lr & 7) << 4);
                bf16x8 bfr = *(bf16x8*)((char*)Ws + bbyte);
                acc[f] = __builtin_amdgcn_mfma_f32_16x16x32_bf16(af, bfr, acc[f], 0, 0, 0);
            }
        }
    }

    int gr0 = m0 + 16 * w + 4 * lg;
#pragma unroll
    for (int f = 0; f < 4; f++) {
        int gc = n0 + 16 * f + lr;
        float bv = bias[gc];
#pragma unroll
        for (int r = 0; r < 4; r++) {
            int gm = gr0 + r;
            float v = acc[f][r] + bv;
            if (MODE == 3) v = 0.5f * v * (1.0f + erff(v * 0.70710678118654752f));
            if (MODE == 2 || MODE == 4) v += resid[(size_t)gm * EMBED + gc];
            if (MODE == 0 || MODE == 3) {
                outb[(size_t)gm * N + gc] = f2b(v);
            } else if (MODE == 1) {
                int b_ = gm >> 7, t_ = gm & 127, h_ = gc >> 6, d_ = gc & 63;
                outf[(((size_t)(b_ * HEADS + h_)) * SEQA + CARRY + t_) * HDIM + d_] = v;
            } else if (MODE == 5) {
                if (gc < 1024) {
                    outb[(size_t)gm * EMBED + gc] = f2b(v);
                } else {
                    int which = gc >> 10;
                    int gc2 = gc & 1023;
                    int b_ = gm >> 7, t_ = gm & 127, h_ = gc2 >> 6, d_ = gc2 & 63;
                    float* dst = (which == 1) ? outf : outf2;
                    dst[(((size_t)(b_ * HEADS + h_)) * SEQA + CARRY + t_) * HDIM + d_] = v;
                }
            } else {
                outf[(size_t)gm * EMBED + gc] = v;
            }
        }
    }
}

// ---------------- split-K GEMM -> fp32 partials ----------------
__global__ __launch_bounds__(256) void gemm_splitk(const u16* __restrict__ A,
                                                   const u16* __restrict__ WT,
                                                   float* __restrict__ part,
                                                   int N, int Ktot, int Klen) {
    __shared__ u16 As[64 * 64];
    __shared__ u16 Ws[64 * 64];
    int tid = threadIdx.x;
    int m0 = blockIdx.y * 64, n0 = blockIdx.x * 64;
    int k0s = blockIdx.z * Klen;
    int w = tid >> 6, l = tid & 63, lr = l & 15, lg = l >> 4;
    f32x4 acc[4] = {};

    const u16* Ag = A + (size_t)m0 * Ktot;
    const u16* Wg = WT + (size_t)n0 * Ktot;

    for (int k0 = k0s; k0 < k0s + Klen; k0 += 64) {
        __syncthreads();
        stage2(Ag + k0, Wg + k0, As, Ws, w, l, Ktot);
        __syncthreads();
#pragma unroll
        for (int ks = 0; ks < 2; ks++) {
            int abyte = ((16 * w + lr) * 128 + lg * 16 + ks * 64) ^ ((lr & 7) << 4);
            bf16x8 af = *(bf16x8*)((char*)As + abyte);
#pragma unroll
            for (int f = 0; f < 4; f++) {
                int bbyte = ((16 * f + lr) * 128 + lg * 16 + ks * 64) ^ ((lr & 7) << 4);
                bf16x8 bfr = *(bf16x8*)((char*)Ws + bbyte);
                acc[f] = __builtin_amdgcn_mfma_f32_16x16x32_bf16(af, bfr, acc[f], 0, 0, 0);
            }
        }
    }

    float* pbase = part + (size_t)blockIdx.z * MROWS * N;
    int gr0 = m0 + 16 * w + 4 * lg;
#pragma unroll
    for (int f = 0; f < 4; f++) {
        int gc = n0 + 16 * f + lr;
#pragma unroll
        for (int r = 0; r < 4; r++)
            pbase[(size_t)(gr0 + r) * N + gc] = acc[f][r];
    }
}

// ---- combine (final): out = resid + bias + sum_s part[s] ----
template <int NS>
__global__ __launch_bounds__(256) void combine_add(const float* __restrict__ part,
                                                   const float* __restrict__ bias,
                                                   const float* __restrict__ resid,
                                                   float* __restrict__ out) {
    size_t e = ((size_t)blockIdx.x * 256 + threadIdx.x) * 4;
    int n0 = (int)(e & 1023);
    float4 v = *(const float4*)(resid + e);
    float4 b = *(const float4*)(bias + n0);
    v.x += b.x; v.y += b.y; v.z += b.z; v.w += b.w;
#pragma unroll
    for (int s = 0; s < NS; s++) {
        float4 p = *(const float4*)(part + (size_t)s * MROWS * EMBED + e);
        v.x += p.x; v.y += p.y; v.z += p.z; v.w += p.w;
    }
    *(float4*)(out + e) = v;
}

// ---- combine proj + LN2 fused ----
__global__ __launch_bounds__(256) void combine_ln(const float* __restrict__ part,
                                                  const float* __restrict__ bias,
                                                  const float* __restrict__ resid,
                                                  const float* __restrict__ ln_s,
                                                  const float* __restrict__ ln_b,
                                                  float* __restrict__ out,
                                                  u16* __restrict__ outb) {
    int row = blockIdx.x, tid = threadIdx.x;
    size_t base = (size_t)row * EMBED + tid * 4;
    float4 v = *(const float4*)(resid + base);
    float4 b = *(const float4*)(bias + tid * 4);
    v.x += b.x; v.y += b.y; v.z += b.z; v.w += b.w;
#pragma unroll
    for (int s = 0; s < 2; s++) {
        float4 p = *(const float4*)(part + (size_t)s * MROWS * EMBED + base);
        v.x += p.x; v.y += p.y; v.z += p.z; v.w += p.w;
    }
    *(float4*)(out + base) = v;

    float s1 = v.x + v.y + v.z + v.w;
    float s2 = v.x * v.x + v.y * v.y + v.z * v.z + v.w * v.w;
    for (int o = 32; o > 0; o >>= 1) {
        s1 += __shfl_down(s1, o, 64);
        s2 += __shfl_down(s2, o, 64);
    }
    __shared__ float ls[8], ls2[8];
    int wid = tid >> 6, lane = tid & 63;
    if (lane == 0) { ls[wid] = s1; ls2[wid] = s2; }
    __syncthreads();
    if (tid == 0) {
        float S = 0.f, S2 = 0.f;
        for (int i = 0; i < 4; i++) { S += ls[i]; S2 += ls2[i]; }
        float mu = S * (1.0f / EMBED);
        float var = S2 * (1.0f / EMBED) - mu * mu;
        ls[0] = mu;
        ls2[0] = rsqrtf(var + 1e-5f);
    }
    __syncthreads();
    float mu = ls[0], rstd = ls2[0];
    float sc[4], bi[4];
    *(float4*)sc = ((const float4*)ln_s)[tid];
    *(float4*)bi = ((const float4*)ln_b)[tid];
    u16 o0 = f2b((v.x - mu) * rstd * sc[0] + bi[0]);
    u16 o1 = f2b((v.y - mu) * rstd * sc[1] + bi[1]);
    u16 o2 = f2b((v.z - mu) * rstd * sc[2] + bi[2]);
    u16 o3 = f2b((v.w - mu) * rstd * sc[3] + bi[3]);
    unsigned int u0 = (unsigned int)o0 | ((unsigned int)o1 << 16);
    unsigned int u1 = (unsigned int)o2 | ((unsigned int)o3 << 16);
    uint2 pk = {u0, u1};
    *(uint2*)(outb + base) = pk;
}

// ---------------- MFMA flash attention (round-5 structure + XCD pairing) ----
// 1D grid of 2048 blocks, 256 threads. Decode: sp = g&7 (XCD slot),
// qh = (g>>3)&1, bh = g>>4. The two qh blocks of a (bh,sp) pair are 8 apart
// in linear id -> same XCD (round-robin) -> second carry read hits L2.
// qh==0 blocks write carry through to k_all/v_all (exactly-once copy).
__global__ __launch_bounds__(256) void attn_mfma_split(const u16* __restrict__ qb,
                                                       const float* __restrict__ kc,
                                                       const float* __restrict__ vc,
                                                       float* __restrict__ k_all,
                                                       float* __restrict__ v_all,
                                                       float* __restrict__ part_acc,
                                                       float* __restrict__ part_m,
                                                       float* __restrict__ part_l) {
    __shared__ u16 Ks[64 * 64];
    __shared__ u16 Vt[64 * 64];
    __shared__ u16 Ps[64 * 64];

    int g = blockIdx.x;
    int sp = g & 7;
    int qh = (g >> 3) & 1;
    int bh = g >> 4;
    int b = bh >> 4, h = bh & 15;
    int q0 = qh * 64;
    int tid = threadIdx.x;
    int w = tid >> 6, l = tid & 63, lr = l & 15, lg = l >> 4;
    const bool WR = (qh == 0);

    bf16x8 qf0, qf1;
    {
        const u16* qrow = qb + (size_t)(b * TLEN + q0 + 16 * w + lr) * EMBED + h * HDIM;
        qf0 = *(const bf16x8*)(qrow + 8 * lg);
        qf1 = *(const bf16x8*)(qrow + 8 * lg + 32);
    }

    const float* kcb = kc + (size_t)bh * CARRY * HDIM;
    const float* vcb = vc + (size_t)bh * CARRY * HDIM;
    const float* kb = k_all + (size_t)bh * SEQA * HDIM;
    const float* vb = v_all + (size_t)bh * SEQA * HDIM;
    float* kwr = k_all + (size_t)bh * SEQA * HDIM;
    float* vwr = v_all + (size_t)bh * SEQA * HDIM;

    float m_run[4], l_run[4];
    f32x4 oacc[4] = {};
#pragma unroll
    for (int r = 0; r < 4; r++) { m_run[r] = -1e30f; l_run[r] = 0.f; }

    int nt = (CARRY + q0 + 64) >> 6;      // 65 or 66
    int tps = (nt + NSPLIT - 1) / NSPLIT; // 9
    int kt0 = sp * tps;
    int kt1 = min(kt0 + tps, nt);

    // staging thread geometry
    int krow = tid >> 4;          // +16p -> K rows
    int vrow4 = (tid >> 4) * 4;   // +p   -> V rows (4 consecutive)
    int col = (tid & 15) * 4;     // fp32 col

    float4 kA[4], vA[4], kB[4], vB[4];

    // prologue: load first tile into A
    {
        bool cn = kt0 < 64;
        const float* ksrc = cn ? kcb : kb;
        const float* vsrc = cn ? vcb : vb;
#pragma unroll
        for (int p = 0; p < 4; p++)
            kA[p] = *(const float4*)(ksrc + (size_t)(kt0 * 64 + krow + 16 * p) * HDIM + col);
#pragma unroll
        for (int p = 0; p < 4; p++)
            vA[p] = *(const float4*)(vsrc + (size_t)(kt0 * 64 + vrow4 + p) * HDIM + col);
    }

    auto body = [&](float4 (&kc_)[4], float4 (&vc_)[4],
                    float4 (&kn_)[4], float4 (&vn_)[4], int kt) {
        bool carry_t = kt < 64;
        int ktn = kt + 1;
        // prefetch next tile into other reg set (in flight across this tile's compute)
        if (ktn < kt1) {
            bool cn = ktn < 64;
            const float* ksrc = cn ? kcb : kb;
            const float* vsrc = cn ? vcb : vb;
#pragma unroll
            for (int p = 0; p < 4; p++)
                kn_[p] = *(const float4*)(ksrc + (size_t)(ktn * 64 + krow + 16 * p) * HDIM + col);
#pragma unroll
            for (int p = 0; p < 4; p++)
                vn_[p] = *(const float4*)(vsrc + (size_t)(ktn * 64 + vrow4 + p) * HDIM + col);
        }
        // carry write-through (stores fly; never waited in-loop)
        if (WR && carry_t) {
#pragma unroll
            for (int p = 0; p < 4; p++)
                *(float4*)(kwr + (size_t)(kt * 64 + krow + 16 * p) * HDIM + col) = kc_[p];
#pragma unroll
            for (int p = 0; p < 4; p++)
                *(float4*)(vwr + (size_t)(kt * 64 + vrow4 + p) * HDIM + col) = vc_[p];
        }
        bar_plain(); // previous tile's PV reads of Ks/Vt done
        // K -> LDS (bf16, swizzled)
#pragma unroll
        for (int p = 0; p < 4; p++) {
            int s = krow + 16 * p;
            u16 t0 = f2b(kc_[p].x), t1 = f2b(kc_[p].y), t2 = f2b(kc_[p].z), t3 = f2b(kc_[p].w);
            unsigned int a = (unsigned int)t0 | ((unsigned int)t1 << 16);
            unsigned int bq = (unsigned int)t2 | ((unsigned int)t3 << 16);
            uint2 pk = {a, bq};
            *(uint2*)((char*)Ks + ((s * 128 + col * 2) ^ ((s & 7) << 4))) = pk;
        }
        // V -> LDS transposed: 4x4 register transpose, b64 writes
#pragma unroll
        for (int i = 0; i < 4; i++) {
            int d = col + i;
            u16 e0 = f2b(((const float*)&vc_[0])[i]);
            u16 e1 = f2b(((const float*)&vc_[1])[i]);
            u16 e2 = f2b(((const float*)&vc_[2])[i]);
            u16 e3 = f2b(((const float*)&vc_[3])[i]);
            unsigned int a = (unsigned int)e0 | ((unsigned int)e1 << 16);
            unsigned int bq = (unsigned int)e2 | ((unsigned int)e3 << 16);
            uint2 pk = {a, bq};
            *(uint2*)((char*)Vt + ((d * 128 + vrow4 * 2) ^ ((d & 7) << 4))) = pk;
        }
        bar_lgkm(); // staging visible to all waves (vmcnt NOT drained)

        // ==== compute ====
        float x[4][4];
#pragma unroll
        for (int f = 0; f < 4; f++) {
            int row = 16 * f + lr;
            int swz = (row & 7) << 4;
            bf16x8 kf0 = *(bf16x8*)((char*)Ks + ((row * 128 + 16 * lg) ^ swz));
            bf16x8 kf1 = *(bf16x8*)((char*)Ks + ((row * 128 + 16 * lg + 64) ^ swz));
            f32x4 z = {};
            z = __builtin_amdgcn_mfma_f32_16x16x32_bf16(qf0, kf0, z, 0, 0, 0);
            z = __builtin_amdgcn_mfma_f32_16x16x32_bf16(qf1, kf1, z, 0, 0, 0);
#pragma unroll
            for (int r = 0; r < 4; r++) x[f][r] = z[r] * 0.125f;
        }
        if (kt * 64 + 63 > CARRY + q0 + 16 * w) {
#pragma unroll
            for (int f = 0; f < 4; f++) {
                int sg = kt * 64 + 16 * f + lr;
#pragma unroll
                for (int r = 0; r < 4; r++) {
                    int tg = q0 + 16 * w + 4 * lg + r;
                    if (sg > CARRY + tg) x[f][r] = -1e30f;
                }
            }
        }
#pragma unroll
        for (int r = 0; r < 4; r++) {
            float mt = fmaxf(fmaxf(x[0][r], x[1][r]), fmaxf(x[2][r], x[3][r]));
            mt = fmaxf(mt, __shfl_xor(mt, 1, 64));
            mt = fmaxf(mt, __shfl_xor(mt, 2, 64));
            mt = fmaxf(mt, __shfl_xor(mt, 4, 64));
            mt = fmaxf(mt, __shfl_xor(mt, 8, 64));
            float mn = fmaxf(m_run[r], mt);
            float fs = __expf(m_run[r] - mn);
            m_run[r] = mn;
            float s = 0.f;
#pragma unroll
            for (int f = 0; f < 4; f++) {
                float p = __expf(x[f][r] - mn);
                x[f][r] = p;
                s += p;
            }
            s += __shfl_xor(s, 1, 64);
            s += __shfl_xor(s, 2, 64);
            s += __shfl_xor(s, 4, 64);
            s += __shfl_xor(s, 8, 64);
            l_run[r] = l_run[r] * fs + s;
#pragma unroll
            for (int f2 = 0; f2 < 4; f2++) oacc[f2][r] *= fs;
        }
#pragma unroll
        for (int f = 0; f < 4; f++) {
#pragma unroll
            for (int r = 0; r < 4; r++) {
                int row = 16 * w + 4 * lg + r;
                int byte = (row * 128 + (16 * f + lr) * 2) ^ ((row & 7) << 4);
                *(u16*)((char*)Ps + byte) = f2b(x[f][r]);
            }
        }
        {
            int prow = 16 * w + lr;
            int pswz = (prow & 7) << 4;
            bf16x8 pa0 = *(bf16x8*)((char*)Ps + ((prow * 128 + 16 * lg) ^ pswz));
            bf16x8 pa1 = *(bf16x8*)((char*)Ps + ((prow * 128 + 16 * lg + 64) ^ pswz));
#pragma unroll
            for (int f2 = 0; f2 < 4; f2++) {
                int d = 16 * f2 + lr;
                int vswz = (d & 7) << 4;
                bf16x8 vf0 = *(bf16x8*)((char*)Vt + ((d * 128 + 16 * lg) ^ vswz));
                bf16x8 vf1 = *(bf16x8*)((char*)Vt + ((d * 128 + 16 * lg + 64) ^ vswz));
                oacc[f2] = __builtin_amdgcn_mfma_f32_16x16x32_bf16(pa0, vf0, oacc[f2], 0, 0, 0);
                oacc[f2] = __builtin_amdgcn_mfma_f32_16x16x32_bf16(pa1, vf1, oacc[f2], 0, 0, 0);
            }
        }
    };

    for (int kt = kt0; kt < kt1; kt += 2) {
        body(kA, vA, kB, vB, kt);
        if (kt + 1 < kt1) body(kB, vB, kA, vA, kt + 1);
    }

    int p = (bh * 2 + qh) * NSPLIT + sp;
    if (lr == 0) {
#pragma unroll
        for (int r = 0; r < 4; r++) {
            int row = 16 * w + 4 * lg + r;
            part_m[(size_t)p * 64 + row] = m_run[r];
            part_l[(size_t)p * 64 + row] = l_run[r];
        }
    }
#pragma unroll
    for (int f2 = 0; f2 < 4; f2++) {
#pragma unroll
        for (int r = 0; r < 4; r++) {
            int row = 16 * w + 4 * lg + r;
            part_acc[(size_t)p * 4096 + row * 64 + 16 * f2 + lr] = oacc[f2][r];
        }
    }
}

// ---- attn combine: merge NSPLIT kv-splits -> ctx bf16 ----
__global__ __launch_bounds__(256) void attn_combine(const float* __restrict__ part_acc,
                                                    const float* __restrict__ part_m,
                                                    const float* __restrict__ part_l,
                                                    u16* __restrict__ ctx) {
    int g = blockIdx.x;
    int bh = g >> 1, qh = g & 1, b = bh >> 4, h = bh & 15;
    int t = threadIdx.x;
    int r = t >> 2, c0 = (t & 3) * 16;
    int p0 = g * NSPLIT;

    float ms[NSPLIT];
    float M = -1e30f;
#pragma unroll
    for (int s = 0; s < NSPLIT; s++) {
        ms[s] = part_m[(size_t)(p0 + s) * 64 + r];
        M = fmaxf(M, ms[s]);
    }
    float wgt[NSPLIT];
    float L = 0.f;
#pragma unroll
    for (int s = 0; s < NSPLIT; s++) {
        wgt[s] = __expf(ms[s] - M);
        L += wgt[s] * part_l[(size_t)(p0 + s) * 64 + r];
    }
    float inv = 1.0f / L;

    size_t grow = (size_t)(b * TLEN + qh * 64 + r) * EMBED + h * HDIM + c0;
#pragma unroll
    for (int j = 0; j < 16; j += 4) {
        float4 a = {0.f, 0.f, 0.f, 0.f};
#pragma unroll
        for (int s = 0; s < NSPLIT; s++) {
            float4 p = *(const float4*)(part_acc + (size_t)(p0 + s) * 4096 + r * 64 + c0 + j);
            a.x += wgt[s] * p.x; a.y += wgt[s] * p.y; a.z += wgt[s] * p.z; a.w += wgt[s] * p.w;
        }
        u16 o0 = f2b(a.x * inv), o1 = f2b(a.y * inv), o2 = f2b(a.z * inv), o3 = f2b(a.w * inv);
        unsigned int u0 = (unsigned int)o0 | ((unsigned int)o1 << 16);
        unsigned int u1 = (unsigned int)o2 | ((unsigned int)o3 << 16);
        uint2 pk = {u0, u1};
        *(uint2*)(ctx + grow + j) = pk;
    }
}

// ---------------- fallback non-split attention (reads k_all/v_all) ----------------
__global__ __launch_bounds__(256) void attn_mfma(const u16* __restrict__ qb,
                                                 const float* __restrict__ k_all,
                                                 const float* __restrict__ v_all,
                                                 u16* __restrict__ ctx) {
    __shared__ u16 Ks[64 * 64];
    __shared__ u16 Vt[64 * 64];
    __shared__ u16 Ps[64 * 64];

    int bh = blockIdx.x, b = bh >> 4, h = bh & 15;
    int q0 = blockIdx.y * 64;
    int tid = threadIdx.x;
    int w = tid >> 6, l = tid & 63, lr = l & 15, lg = l >> 4;

    bf16x8 qf0, qf1;
    {
        const u16* qrow = qb + (size_t)(b * TLEN + q0 + 16 * w + lr) * EMBED + h * HDIM;
        qf0 = *(const bf16x8*)(qrow + 8 * lg);
        qf1 = *(const bf16x8*)(qrow + 8 * lg + 32);
    }
    const float* kb = k_all + (size_t)bh * SEQA * HDIM;
    const float* vb = v_all + (size_t)bh * SEQA * HDIM;

    float m_run[4], l_run[4];
    f32x4 oacc[4] = {};
#pragma unroll
    for (int r = 0; r < 4; r++) { m_run[r] = -1e30f; l_run[r] = 0.f; }

    int nt = (CARRY + q0 + 64) >> 6;
    for (int kt = 0; kt < nt; kt++) {
        __syncthreads();
#pragma unroll
        for (int p = 0; p < 4; p++) {
            int s = (tid >> 4) + 16 * p, c = (tid & 15) * 4;
            float4 kv = *(const float4*)(kb + (size_t)(kt * 64 + s) * HDIM + c);
            u16 t0 = f2b(kv.x), t1 = f2b(kv.y), t2 = f2b(kv.z), t3 = f2b(kv.w);
            unsigned int a = (unsigned int)t0 | ((unsigned int)t1 << 16);
            unsigned int bq = (unsigned int)t2 | ((unsigned int)t3 << 16);
            uint2 pk = {a, bq};
            int byte = (s * 128 + c * 2) ^ ((s & 7) << 4);
            *(uint2*)((char*)Ks + byte) = pk;
        }
        {
            int d = tid & 63;
            u16 tmp[16];
#pragma unroll
            for (int q = 0; q < 16; q++)
                tmp[q] = f2b(vb[(size_t)(kt * 64 + 16 * w + q) * HDIM + d]);
            int b0 = (d * 128 + 32 * w) ^ ((d & 7) << 4);
            int b1 = (d * 128 + 32 * w + 16) ^ ((d & 7) << 4);
            *(bf16x8*)((char*)Vt + b0) = *(bf16x8*)&tmp[0];
            *(bf16x8*)((char*)Vt + b1) = *(bf16x8*)&tmp[8];
        }
        __syncthreads();

        float x[4][4];
#pragma unroll
        for (int f = 0; f < 4; f++) {
            int row = 16 * f + lr;
            int swz = (row & 7) << 4;
            bf16x8 kf0 = *(bf16x8*)((char*)Ks + ((row * 128 + 16 * lg) ^ swz));
            bf16x8 kf1 = *(bf16x8*)((char*)Ks + ((row * 128 + 16 * lg + 64) ^ swz));
            f32x4 z = {};
            z = __builtin_amdgcn_mfma_f32_16x16x32_bf16(qf0, kf0, z, 0, 0, 0);
            z = __builtin_amdgcn_mfma_f32_16x16x32_bf16(qf1, kf1, z, 0, 0, 0);
#pragma unroll
            for (int r = 0; r < 4; r++) x[f][r] = z[r] * 0.125f;
        }
        if (kt * 64 + 63 > CARRY + q0 + 16 * w) {
#pragma unroll
            for (int f = 0; f < 4; f++) {
                int sg = kt * 64 + 16 * f + lr;
#pragma unroll
                for (int r = 0; r < 4; r++) {
                    int tg = q0 + 16 * w + 4 * lg + r;
                    if (sg > CARRY + tg) x[f][r] = -1e30f;
                }
            }
        }
#pragma unroll
        for (int r = 0; r < 4; r++) {
            float mt = fmaxf(fmaxf(x[0][r], x[1][r]), fmaxf(x[2][r], x[3][r]));
            mt = fmaxf(mt, __shfl_xor(mt, 1, 64));
            mt = fmaxf(mt, __shfl_xor(mt, 2, 64));
            mt = fmaxf(mt, __shfl_xor(mt, 4, 64));
            mt = fmaxf(mt, __shfl_xor(mt, 8, 64));
            float mn = fmaxf(m_run[r], mt);
            float fs = __expf(m_run[r] - mn);
            m_run[r] = mn;
            float s = 0.f;
#pragma unroll
            for (int f = 0; f < 4; f++) {
                float p = __expf(x[f][r] - mn);
                x[f][r] = p;
                s += p;
            }
            s += __shfl_xor(s, 1, 64);
            s += __shfl_xor(s, 2, 64);
            s += __shfl_xor(s, 4, 64);
            s += __shfl_xor(s, 8, 64);
            l_run[r] = l_run[r] * fs + s;
#pragma unroll
            for (int f2 = 0; f2 < 4; f2++) oacc[f2][r] *= fs;
        }
#pragma unroll
        for (int f = 0; f < 4; f++) {
#pragma unroll
            for (int r = 0; r < 4; r++) {
                int row = 16 * w + 4 * lg + r;
                int byte = (row * 128 + (16 * f + lr) * 2) ^ ((row & 7) << 4);
                *(u16*)((char*)Ps + byte) = f2b(x[f][r]);
            }
        }
        {
            int prow = 16 * w + lr;
            int pswz = (prow & 7) << 4;
            bf16x8 pa0 = *(bf16x8*)((char*)Ps + ((prow * 128 + 16 * lg) ^ pswz));
            bf16x8 pa1 = *(bf16x8*)((char*)Ps + ((prow * 128 + 16 * lg + 64) ^ pswz));
#pragma unroll
            for (int f2 = 0; f2 < 4; f2++) {
                int d = 16 * f2 + lr;
                int vswz = (d & 7) << 4;
                bf16x8 vf0 = *(bf16x8*)((char*)Vt + ((d * 128 + 16 * lg) ^ vswz));
                bf16x8 vf1 = *(bf16x8*)((char*)Vt + ((d * 128 + 16 * lg + 64) ^ vswz));
                oacc[f2] = __builtin_amdgcn_mfma_f32_16x16x32_bf16(pa0, vf0, oacc[f2], 0, 0, 0);
                oacc[f2] = __builtin_amdgcn_mfma_f32_16x16x32_bf16(pa1, vf1, oacc[f2], 0, 0, 0);
            }
        }
    }
#pragma unroll
    for (int r = 0; r < 4; r++) {
        float inv = 1.0f / l_run[r];
        size_t grow = (size_t)(b * TLEN + q0 + 16 * w + 4 * lg + r) * EMBED + h * HDIM;
#pragma unroll
        for (int f2 = 0; f2 < 4; f2++)
            ctx[grow + 16 * f2 + lr] = f2b(oacc[f2][r] * inv);
    }
}

extern "C" void kernel_launch(void* const* d_in, const int* in_sizes, int n_in,
                              void* d_out, int out_size, void* d_ws, size_t ws_size,
                              hipStream_t stream) {
    const float* hidden = (const float*)d_in[0];
    const float* key_carry = (const float*)d_in[1];
    const float* value_carry = (const float*)d_in[2];
    const float* ln1_s = (const float*)d_in[3];
    const float* ln1_b = (const float*)d_in[4];
    const float* wq = (const float*)d_in[5];
    const float* bq = (const float*)d_in[6];
    const float* wk = (const float*)d_in[7];
    const float* bk = (const float*)d_in[8];
    const float* wv = (const float*)d_in[9];
    const float* bv = (const float*)d_in[10];
    const float* wo = (const float*)d_in[11];
    const float* bo = (const float*)d_in[12];
    const float* ln2_s = (const float*)d_in[13];
    const float* ln2_b = (const float*)d_in[14];
    const float* w1 = (const float*)d_in[15];
    const float* b1 = (const float*)d_in[16];
    const float* w2 = (const float*)d_in[17];
    const float* b2 = (const float*)d_in[18];

    float* out_hidden = (float*)d_out;
    float* k_all = out_hidden + (size_t)MROWS * EMBED;
    float* v_all = k_all + (size_t)BATCH * HEADS * SEQA * HDIM;

    u16* wsu = (u16*)d_ws;
    u16* wqkvT = wsu;                  // [3072][1024]
    u16* woT = wsu + 3145728;          // [1024][1024]
    u16* w1T = wsu + 4194304;          // [4096][1024]
    u16* w2T = wsu + 8388608;          // [1024][4096]
    u16* xb  = wsu + 12582912;
    u16* qbb = wsu + 13631488;
    u16* ctxb = wsu + 14680064;
    u16* fb  = wsu + 15728640;
    u16* h1b = wsu + 16777216;         // [1024][4096]
    float* bias_qkv = (float*)(wsu + 20971520);          // 3072 f32
    float* part = (float*)(wsu + 20977664);
    const size_t nparts = (size_t)256 * NSPLIT;          // (bh*2+qh) x splits
    const size_t need = (size_t)20977664 * 2 +
                        (nparts * 4096 + 2 * nparts * 64) * 4;

    transpose_all<<<dim3(16, 16, 12), 256, 0, stream>>>(wq, wk, wv, wo, w1, w2, bq, bk, bv,
                                                        wqkvT, woT, w1T, w2T, bias_qkv);

    ln_kernel<<<MROWS, 256, 0, stream>>>(hidden, ln1_s, ln1_b, xb);

    if (ws_size >= need) {
        // fused QKV: Q->qbb bf16, K/V -> k_all/v_all new rows (4096..4223)
        gemm_bf16<5><<<dim3(48, 16), 256, 0, stream>>>(xb, wqkvT, bias_qkv, nullptr,
                                                       k_all, v_all, qbb, 3072, EMBED);
        float* part_acc = part;
        float* part_m = part + nparts * 4096;
        float* part_l = part_m + nparts * 64;
        attn_mfma_split<<<2048, 256, 0, stream>>>(
            qbb, key_carry, value_carry, k_all, v_all, part_acc, part_m, part_l);
        attn_combine<<<256, 256, 0, stream>>>(part_acc, part_m, part_l, ctxb);

        gemm_splitk<<<dim3(16, 16, 2), 256, 0, stream>>>(ctxb, woT, part, EMBED, EMBED, 512);
        combine_ln<<<1024, 256, 0, stream>>>(part, bo, hidden, ln2_s, ln2_b, out_hidden, fb);

        gemm_bf16<3><<<dim3(64, 16), 256, 0, stream>>>(fb, w1T, b1, nullptr, nullptr, nullptr,
                                                       h1b, FFDIM, EMBED);
        gemm_splitk<<<dim3(16, 16, 4), 256, 0, stream>>>(h1b, w2T, part, EMBED, FFDIM, 1024);
        combine_add<4><<<1024, 256, 0, stream>>>(part, b2, out_hidden, out_hidden);
    } else {
        // fallback: non-split schedule with explicit carry copy
        copy_carry_kernel<<<2048, 256, 0, stream>>>(
            (const float4*)key_carry, (const float4*)value_carry,
            (float4*)k_all, (float4*)v_all);
        u16* wqT = wqkvT;
        u16* wkT = wqkvT + 1048576;
        u16* wvT = wqkvT + 2097152;
        gemm_bf16<0><<<dim3(16, 16), 256, 0, stream>>>(xb, wqT, bq, nullptr, nullptr, nullptr,
                                                       qbb, EMBED, EMBED);
        gemm_bf16<1><<<dim3(16, 16), 256, 0, stream>>>(xb, wkT, bk, nullptr, k_all, nullptr,
                                                       nullptr, EMBED, EMBED);
        gemm_bf16<1><<<dim3(16, 16), 256, 0, stream>>>(xb, wvT, bv, nullptr, v_all, nullptr,
                                                       nullptr, EMBED, EMBED);
        attn_mfma<<<dim3(BATCH * HEADS, 2), 256, 0, stream>>>(qbb, k_all, v_all, ctxb);
        gemm_bf16<2><<<dim3(16, 16), 256, 0, stream>>>(ctxb, woT, bo, hidden, out_hidden,
                                                       nullptr, nullptr, EMBED, EMBED);
        ln_kernel<<<MROWS, 256, 0, stream>>>(out_hidden, ln2_s, ln2_b, fb);
        gemm_bf16<3><<<dim3(64, 16), 256, 0, stream>>>(fb, w1T, b1, nullptr, nullptr, nullptr,
                                                       h1b, FFDIM, EMBED);
        gemm_bf16<4><<<dim3(16, 16), 256, 0, stream>>>(h1b, w2T, b2, out_hidden, out_hidden,
                                                       nullptr, nullptr, EMBED, FFDIM);
    }
}

// Round 9
// 243.590 us; speedup vs baseline: 1.3004x; 1.0575x over previous
//
#include <hip/hip_runtime.h>
#include <hip/hip_bf16.h>
#include <math.h>

#define EMBED 1024
#define HEADS 16
#define HDIM 64
#define FFDIM 4096
#define BATCH 8
#define TLEN 128
#define CARRY 4096
#define SEQA (CARRY + TLEN)   // 4224
#define MROWS (BATCH * TLEN)  // 1024
#define NSPLIT 8

typedef __attribute__((ext_vector_type(8))) short bf16x8;
typedef __attribute__((ext_vector_type(4))) float f32x4;
typedef unsigned short u16;

static __device__ __forceinline__ u16 f2b(float v) {
    __hip_bfloat16 h = __float2bfloat16(v);
    return *reinterpret_cast<u16*>(&h);
}

typedef const __attribute__((address_space(1))) unsigned int g_u32;
typedef __attribute__((address_space(3))) unsigned int l_u32;
static __device__ __forceinline__ void gl16(const void* g, void* l) {
    __builtin_amdgcn_global_load_lds((g_u32*)g, (l_u32*)l, 16, 0, 0);
}

// barrier that does NOT drain vmcnt (stores/prefetch loads stay in flight)
static __device__ __forceinline__ void bar_lgkm() {
    asm volatile("s_waitcnt lgkmcnt(0)" ::: "memory");
    __builtin_amdgcn_s_barrier();
    __builtin_amdgcn_sched_barrier(0);
}
static __device__ __forceinline__ void bar_plain() {
    __builtin_amdgcn_sched_barrier(0);
    __builtin_amdgcn_s_barrier();
}

// ---------------- carry copy (fallback path only) ----------------
__global__ void copy_carry_kernel(const float4* __restrict__ kc, const float4* __restrict__ vc,
                                  float4* __restrict__ k_all, float4* __restrict__ v_all) {
    const size_t total = (size_t)BATCH * HEADS * CARRY * HDIM / 4;
    const size_t DH = (size_t)SEQA * HDIM / 4;
    for (size_t e = (size_t)blockIdx.x * blockDim.x + threadIdx.x; e < total;
         e += (size_t)gridDim.x * blockDim.x) {
        size_t bh = e >> 16;
        size_t rem = e & 65535;
        size_t d = bh * DH + rem;
        k_all[d] = kc[e];
        v_all[d] = vc[e];
    }
}

// ---------------- LayerNorm fp32 in -> bf16 out ----------------
__global__ __launch_bounds__(256) void ln_kernel(const float* __restrict__ in,
                                                 const float* __restrict__ scale,
                                                 const float* __restrict__ bias,
                                                 u16* __restrict__ out) {
    int row = blockIdx.x;
    int tid = threadIdx.x;
    const float4* rin = (const float4*)(in + (size_t)row * EMBED);
    float4 v = rin[tid];
    float s = v.x + v.y + v.z + v.w;
    float s2 = v.x * v.x + v.y * v.y + v.z * v.z + v.w * v.w;
    for (int o = 32; o > 0; o >>= 1) {
        s += __shfl_down(s, o, 64);
        s2 += __shfl_down(s2, o, 64);
    }
    __shared__ float ls[8], ls2[8];
    int wid = tid >> 6, lane = tid & 63;
    if (lane == 0) { ls[wid] = s; ls2[wid] = s2; }
    __syncthreads();
    if (tid == 0) {
        float S = 0.f, S2 = 0.f;
        for (int i = 0; i < 4; i++) { S += ls[i]; S2 += ls2[i]; }
        float mu = S * (1.0f / EMBED);
        float var = S2 * (1.0f / EMBED) - mu * mu;
        ls[0] = mu;
        ls2[0] = rsqrtf(var + 1e-5f);
    }
    __syncthreads();
    float mu = ls[0], rstd = ls2[0];
    float sc[4], bi[4], xin[4];
    *(float4*)sc = ((const float4*)scale)[tid];
    *(float4*)bi = ((const float4*)bias)[tid];
    *(float4*)xin = v;
    u16 o0 = f2b((xin[0] - mu) * rstd * sc[0] + bi[0]);
    u16 o1 = f2b((xin[1] - mu) * rstd * sc[1] + bi[1]);
    u16 o2 = f2b((xin[2] - mu) * rstd * sc[2] + bi[2]);
    u16 o3 = f2b((xin[3] - mu) * rstd * sc[3] + bi[3]);
    unsigned int u0 = (unsigned int)o0 | ((unsigned int)o1 << 16);
    unsigned int u1 = (unsigned int)o2 | ((unsigned int)o3 << 16);
    uint2 pk = {u0, u1};
    *(uint2*)(out + (size_t)row * EMBED + tid * 4) = pk;
}

// ---------------- all weight transposes in ONE dispatch ----------------
__global__ __launch_bounds__(256) void transpose_all(const float* __restrict__ wq,
                                                     const float* __restrict__ wk,
                                                     const float* __restrict__ wv,
                                                     const float* __restrict__ wo,
                                                     const float* __restrict__ w1,
                                                     const float* __restrict__ w2,
                                                     const float* __restrict__ bq,
                                                     const float* __restrict__ bk,
                                                     const float* __restrict__ bv,
                                                     u16* __restrict__ wqkvT,
                                                     u16* __restrict__ woT,
                                                     u16* __restrict__ w1T,
                                                     u16* __restrict__ w2T,
                                                     float* __restrict__ bias_qkv) {
    __shared__ float Ls[64][65];
    int z = blockIdx.z;
    int bx = blockIdx.x, by = blockIdx.y;
    const float* W;
    u16* WT;
    int K, N;
    if (z < 4) {
        W = (z == 0) ? wq : (z == 1) ? wk : (z == 2) ? wv : wo;
        WT = (z < 3) ? (wqkvT + (size_t)z * 1024 * 1024) : woT;
        K = 1024; N = 1024;
    } else if (z < 8) {
        W = w1; WT = w1T; K = 1024; N = 4096; bx += (z - 4) * 16;
    } else {
        W = w2; WT = w2T; K = 4096; N = 1024; by += (z - 8) * 16;
    }
    int tid = threadIdx.x;
    if (z == 3 && blockIdx.y == 0 && blockIdx.x < 12) {
        int i = blockIdx.x * 256 + tid;
        bias_qkv[i] = (i < 1024) ? bq[i] : (i < 2048) ? bk[i - 1024] : bv[i - 2048];
    }
    int k0 = by * 64, n0 = bx * 64;
#pragma unroll
    for (int p = 0; p < 4; p++) {
        int r = (tid >> 4) + 16 * p, c = (tid & 15) * 4;
        float4 v = *(const float4*)(W + (size_t)(k0 + r) * N + n0 + c);
        Ls[r][c] = v.x; Ls[r][c + 1] = v.y; Ls[r][c + 2] = v.z; Ls[r][c + 3] = v.w;
    }
    __syncthreads();
#pragma unroll
    for (int p = 0; p < 4; p++) {
        int n = (tid >> 4) + 16 * p, k4 = (tid & 15) * 4;
        u16 o0 = f2b(Ls[k4][n]), o1 = f2b(Ls[k4 + 1][n]);
        u16 o2 = f2b(Ls[k4 + 2][n]), o3 = f2b(Ls[k4 + 3][n]);
        unsigned int a = (unsigned int)o0 | ((unsigned int)o1 << 16);
        unsigned int b = (unsigned int)o2 | ((unsigned int)o3 << 16);
        uint2 pk = {a, b};
        *(uint2*)(WT + (size_t)(n0 + n) * K + k0 + k4) = pk;
    }
}

// ======== shared GEMM staging: global_load_lds(16B) + XOR swizzle ========
static __device__ __forceinline__ void stage2(const u16* __restrict__ Ag,
                                              const u16* __restrict__ Wg,
                                              u16* As, u16* Ws,
                                              int w, int l, int K) {
    int r0 = 16 * w + (l >> 3);
    int scol = ((l & 7) ^ (l >> 3)) * 8;
    char* a0 = (char*)As + w * 2048;
    char* w0 = (char*)Ws + w * 2048;
    gl16(Ag + (size_t)r0 * K + scol, a0);
    gl16(Ag + (size_t)(r0 + 8) * K + scol, a0 + 1024);
    gl16(Wg + (size_t)r0 * K + scol, w0);
    gl16(Wg + (size_t)(r0 + 8) * K + scol, w0 + 1024);
}

// ---------------- bf16 MFMA GEMM: C[M,N] = A[M,K] @ WT[N,K]^T ----------------
// MODE 5 Q-path pre-scales by 1/8 (exact in bf16) so attention skips it.
template <int MODE>
__global__ __launch_bounds__(256) void gemm_bf16(const u16* __restrict__ A,
                                                 const u16* __restrict__ WT,
                                                 const float* __restrict__ bias,
                                                 const float* __restrict__ resid,
                                                 float* __restrict__ outf,
                                                 float* __restrict__ outf2,
                                                 u16* __restrict__ outb, int N, int K) {
    __shared__ u16 As[64 * 64];
    __shared__ u16 Ws[64 * 64];
    int tid = threadIdx.x;
    int m0 = blockIdx.y * 64, n0 = blockIdx.x * 64;
    int w = tid >> 6, l = tid & 63, lr = l & 15, lg = l >> 4;
    f32x4 acc[4] = {};

    const u16* Ag = A + (size_t)m0 * K;
    const u16* Wg = WT + (size_t)n0 * K;

    for (int k0 = 0; k0 < K; k0 += 64) {
        __syncthreads();
        stage2(Ag + k0, Wg + k0, As, Ws, w, l, K);
        __syncthreads();
#pragma unroll
        for (int ks = 0; ks < 2; ks++) {
            int abyte = ((16 * w + lr) * 128 + lg * 16 + ks * 64) ^ ((lr & 7) << 4);
            bf16x8 af = *(bf16x8*)((char*)As + abyte);
#pragma unroll
            for (int f = 0; f < 4; f++) {
                int bbyte = ((16 * f + lr) * 128 + lg * 16 + ks * 64) ^ ((lr & 7) << 4);
                bf16x8 bfr = *(bf16x8*)((char*)Ws + bbyte);
                acc[f] = __builtin_amdgcn_mfma_f32_16x16x32_bf16(af, bfr, acc[f], 0, 0, 0);
            }
        }
    }

    int gr0 = m0 + 16 * w + 4 * lg;
#pragma unroll
    for (int f = 0; f < 4; f++) {
        int gc = n0 + 16 * f + lr;
        float bv = bias[gc];
#pragma unroll
        for (int r = 0; r < 4; r++) {
            int gm = gr0 + r;
            float v = acc[f][r] + bv;
            if (MODE == 3) v = 0.5f * v * (1.0f + erff(v * 0.70710678118654752f));
            if (MODE == 2 || MODE == 4) v += resid[(size_t)gm * EMBED + gc];
            if (MODE == 0 || MODE == 3) {
                outb[(size_t)gm * N + gc] = f2b(v);
            } else if (MODE == 1) {
                int b_ = gm >> 7, t_ = gm & 127, h_ = gc >> 6, d_ = gc & 63;
                outf[(((size_t)(b_ * HEADS + h_)) * SEQA + CARRY + t_) * HDIM + d_] = v;
            } else if (MODE == 5) {
                if (gc < 1024) {
                    outb[(size_t)gm * EMBED + gc] = f2b(v * 0.125f); // pre-scaled Q
                } else {
                    int which = gc >> 10;
                    int gc2 = gc & 1023;
                    int b_ = gm >> 7, t_ = gm & 127, h_ = gc2 >> 6, d_ = gc2 & 63;
                    float* dst = (which == 1) ? outf : outf2;
                    dst[(((size_t)(b_ * HEADS + h_)) * SEQA + CARRY + t_) * HDIM + d_] = v;
                }
            } else {
                outf[(size_t)gm * EMBED + gc] = v;
            }
        }
    }
}

// ---------------- split-K GEMM -> fp32 partials ----------------
__global__ __launch_bounds__(256) void gemm_splitk(const u16* __restrict__ A,
                                                   const u16* __restrict__ WT,
                                                   float* __restrict__ part,
                                                   int N, int Ktot, int Klen) {
    __shared__ u16 As[64 * 64];
    __shared__ u16 Ws[64 * 64];
    int tid = threadIdx.x;
    int m0 = blockIdx.y * 64, n0 = blockIdx.x * 64;
    int k0s = blockIdx.z * Klen;
    int w = tid >> 6, l = tid & 63, lr = l & 15, lg = l >> 4;
    f32x4 acc[4] = {};

    const u16* Ag = A + (size_t)m0 * Ktot;
    const u16* Wg = WT + (size_t)n0 * Ktot;

    for (int k0 = k0s; k0 < k0s + Klen; k0 += 64) {
        __syncthreads();
        stage2(Ag + k0, Wg + k0, As, Ws, w, l, Ktot);
        __syncthreads();
#pragma unroll
        for (int ks = 0; ks < 2; ks++) {
            int abyte = ((16 * w + lr) * 128 + lg * 16 + ks * 64) ^ ((lr & 7) << 4);
            bf16x8 af = *(bf16x8*)((char*)As + abyte);
#pragma unroll
            for (int f = 0; f < 4; f++) {
                int bbyte = ((16 * f + lr) * 128 + lg * 16 + ks * 64) ^ ((lr & 7) << 4);
                bf16x8 bfr = *(bf16x8*)((char*)Ws + bbyte);
                acc[f] = __builtin_amdgcn_mfma_f32_16x16x32_bf16(af, bfr, acc[f], 0, 0, 0);
            }
        }
    }

    float* pbase = part + (size_t)blockIdx.z * MROWS * N;
    int gr0 = m0 + 16 * w + 4 * lg;
#pragma unroll
    for (int f = 0; f < 4; f++) {
        int gc = n0 + 16 * f + lr;
#pragma unroll
        for (int r = 0; r < 4; r++)
            pbase[(size_t)(gr0 + r) * N + gc] = acc[f][r];
    }
}

// ---- combine (final): out = resid + bias + sum_s part[s] ----
template <int NS>
__global__ __launch_bounds__(256) void combine_add(const float* __restrict__ part,
                                                   const float* __restrict__ bias,
                                                   const float* __restrict__ resid,
                                                   float* __restrict__ out) {
    size_t e = ((size_t)blockIdx.x * 256 + threadIdx.x) * 4;
    int n0 = (int)(e & 1023);
    float4 v = *(const float4*)(resid + e);
    float4 b = *(const float4*)(bias + n0);
    v.x += b.x; v.y += b.y; v.z += b.z; v.w += b.w;
#pragma unroll
    for (int s = 0; s < NS; s++) {
        float4 p = *(const float4*)(part + (size_t)s * MROWS * EMBED + e);
        v.x += p.x; v.y += p.y; v.z += p.z; v.w += p.w;
    }
    *(float4*)(out + e) = v;
}

// ---- combine proj + LN2 fused ----
__global__ __launch_bounds__(256) void combine_ln(const float* __restrict__ part,
                                                  const float* __restrict__ bias,
                                                  const float* __restrict__ resid,
                                                  const float* __restrict__ ln_s,
                                                  const float* __restrict__ ln_b,
                                                  float* __restrict__ out,
                                                  u16* __restrict__ outb) {
    int row = blockIdx.x, tid = threadIdx.x;
    size_t base = (size_t)row * EMBED + tid * 4;
    float4 v = *(const float4*)(resid + base);
    float4 b = *(const float4*)(bias + tid * 4);
    v.x += b.x; v.y += b.y; v.z += b.z; v.w += b.w;
#pragma unroll
    for (int s = 0; s < 2; s++) {
        float4 p = *(const float4*)(part + (size_t)s * MROWS * EMBED + base);
        v.x += p.x; v.y += p.y; v.z += p.z; v.w += p.w;
    }
    *(float4*)(out + base) = v;

    float s1 = v.x + v.y + v.z + v.w;
    float s2 = v.x * v.x + v.y * v.y + v.z * v.z + v.w * v.w;
    for (int o = 32; o > 0; o >>= 1) {
        s1 += __shfl_down(s1, o, 64);
        s2 += __shfl_down(s2, o, 64);
    }
    __shared__ float ls[8], ls2[8];
    int wid = tid >> 6, lane = tid & 63;
    if (lane == 0) { ls[wid] = s1; ls2[wid] = s2; }
    __syncthreads();
    if (tid == 0) {
        float S = 0.f, S2 = 0.f;
        for (int i = 0; i < 4; i++) { S += ls[i]; S2 += ls2[i]; }
        float mu = S * (1.0f / EMBED);
        float var = S2 * (1.0f / EMBED) - mu * mu;
        ls[0] = mu;
        ls2[0] = rsqrtf(var + 1e-5f);
    }
    __syncthreads();
    float mu = ls[0], rstd = ls2[0];
    float sc[4], bi[4];
    *(float4*)sc = ((const float4*)ln_s)[tid];
    *(float4*)bi = ((const float4*)ln_b)[tid];
    u16 o0 = f2b((v.x - mu) * rstd * sc[0] + bi[0]);
    u16 o1 = f2b((v.y - mu) * rstd * sc[1] + bi[1]);
    u16 o2 = f2b((v.z - mu) * rstd * sc[2] + bi[2]);
    u16 o3 = f2b((v.w - mu) * rstd * sc[3] + bi[3]);
    unsigned int u0 = (unsigned int)o0 | ((unsigned int)o1 << 16);
    unsigned int u1 = (unsigned int)o2 | ((unsigned int)o3 << 16);
    uint2 pk = {u0, u1};
    *(uint2*)(outb + base) = pk;
}

// ---------------- MFMA flash attention (R5 structure + defer-max + MFMA row-sum)
// grid (B*H, 2, NSPLIT), 256 threads. qh==0 blocks write carry through.
__global__ __launch_bounds__(256) void attn_mfma_split(const u16* __restrict__ qb,
                                                       const float* __restrict__ kc,
                                                       const float* __restrict__ vc,
                                                       float* __restrict__ k_all,
                                                       float* __restrict__ v_all,
                                                       float* __restrict__ part_acc,
                                                       float* __restrict__ part_m,
                                                       float* __restrict__ part_l) {
    __shared__ u16 Ks[64 * 64];
    __shared__ u16 Vt[64 * 64];
    __shared__ u16 Ps[64 * 64];

    int bh = blockIdx.x, b = bh >> 4, h = bh & 15;
    int qh = blockIdx.y;
    int q0 = qh * 64;
    int sp = blockIdx.z;
    int tid = threadIdx.x;
    int w = tid >> 6, l = tid & 63, lr = l & 15, lg = l >> 4;
    const bool WR = (qh == 0);

    bf16x8 qf0, qf1;
    {
        const u16* qrow = qb + (size_t)(b * TLEN + q0 + 16 * w + lr) * EMBED + h * HDIM;
        qf0 = *(const bf16x8*)(qrow + 8 * lg);
        qf1 = *(const bf16x8*)(qrow + 8 * lg + 32);
    }

    // all-ones bf16 B-fragment for MFMA row-sum
    bf16x8 onesf;
#pragma unroll
    for (int j = 0; j < 8; j++) onesf[j] = (short)0x3F80;

    const float* kcb = kc + (size_t)bh * CARRY * HDIM;
    const float* vcb = vc + (size_t)bh * CARRY * HDIM;
    const float* kb = k_all + (size_t)bh * SEQA * HDIM;
    const float* vb = v_all + (size_t)bh * SEQA * HDIM;
    float* kwr = k_all + (size_t)bh * SEQA * HDIM;
    float* vwr = v_all + (size_t)bh * SEQA * HDIM;

    float m_run[4];
    f32x4 lacc = {};
    f32x4 oacc[4] = {};
#pragma unroll
    for (int r = 0; r < 4; r++) m_run[r] = -1e30f;

    int nt = (CARRY + q0 + 64) >> 6;      // 65 or 66
    int tps = (nt + NSPLIT - 1) / NSPLIT; // 9
    int kt0 = sp * tps;
    int kt1 = min(kt0 + tps, nt);

    // staging thread geometry
    int krow = tid >> 4;          // +16p -> K rows
    int vrow4 = (tid >> 4) * 4;   // +p   -> V rows (4 consecutive)
    int col = (tid & 15) * 4;     // fp32 col

    float4 kA[4], vA[4], kB[4], vB[4];

    // prologue: load first tile into A
    {
        bool cn = kt0 < 64;
        const float* ksrc = cn ? kcb : kb;
        const float* vsrc = cn ? vcb : vb;
#pragma unroll
        for (int p = 0; p < 4; p++)
            kA[p] = *(const float4*)(ksrc + (size_t)(kt0 * 64 + krow + 16 * p) * HDIM + col);
#pragma unroll
        for (int p = 0; p < 4; p++)
            vA[p] = *(const float4*)(vsrc + (size_t)(kt0 * 64 + vrow4 + p) * HDIM + col);
    }

    auto body = [&](float4 (&kc_)[4], float4 (&vc_)[4],
                    float4 (&kn_)[4], float4 (&vn_)[4], int kt) {
        bool carry_t = kt < 64;
        int ktn = kt + 1;
        // prefetch next tile into other reg set (in flight across this tile's compute)
        if (ktn < kt1) {
            bool cn = ktn < 64;
            const float* ksrc = cn ? kcb : kb;
            const float* vsrc = cn ? vcb : vb;
#pragma unroll
            for (int p = 0; p < 4; p++)
                kn_[p] = *(const float4*)(ksrc + (size_t)(ktn * 64 + krow + 16 * p) * HDIM + col);
#pragma unroll
            for (int p = 0; p < 4; p++)
                vn_[p] = *(const float4*)(vsrc + (size_t)(ktn * 64 + vrow4 + p) * HDIM + col);
        }
        // carry write-through (stores fly; never waited in-loop)
        if (WR && carry_t) {
#pragma unroll
            for (int p = 0; p < 4; p++)
                *(float4*)(kwr + (size_t)(kt * 64 + krow + 16 * p) * HDIM + col) = kc_[p];
#pragma unroll
            for (int p = 0; p < 4; p++)
                *(float4*)(vwr + (size_t)(kt * 64 + vrow4 + p) * HDIM + col) = vc_[p];
        }
        bar_plain(); // previous tile's PV reads of Ks/Vt done
        // K -> LDS (bf16, swizzled)
#pragma unroll
        for (int p = 0; p < 4; p++) {
            int s = krow + 16 * p;
            u16 t0 = f2b(kc_[p].x), t1 = f2b(kc_[p].y), t2 = f2b(kc_[p].z), t3 = f2b(kc_[p].w);
            unsigned int a = (unsigned int)t0 | ((unsigned int)t1 << 16);
            unsigned int bq = (unsigned int)t2 | ((unsigned int)t3 << 16);
            uint2 pk = {a, bq};
            *(uint2*)((char*)Ks + ((s * 128 + col * 2) ^ ((s & 7) << 4))) = pk;
        }
        // V -> LDS transposed: 4x4 register transpose, b64 writes
#pragma unroll
        for (int i = 0; i < 4; i++) {
            int d = col + i;
            u16 e0 = f2b(((const float*)&vc_[0])[i]);
            u16 e1 = f2b(((const float*)&vc_[1])[i]);
            u16 e2 = f2b(((const float*)&vc_[2])[i]);
            u16 e3 = f2b(((const float*)&vc_[3])[i]);
            unsigned int a = (unsigned int)e0 | ((unsigned int)e1 << 16);
            unsigned int bq = (unsigned int)e2 | ((unsigned int)e3 << 16);
            uint2 pk = {a, bq};
            *(uint2*)((char*)Vt + ((d * 128 + vrow4 * 2) ^ ((d & 7) << 4))) = pk;
        }
        bar_lgkm(); // staging visible to all waves (vmcnt NOT drained)

        // ==== QK^T (Q pre-scaled by 1/8) ====
        float x[4][4];
#pragma unroll
        for (int f = 0; f < 4; f++) {
            int row = 16 * f + lr;
            int swz = (row & 7) << 4;
            bf16x8 kf0 = *(bf16x8*)((char*)Ks + ((row * 128 + 16 * lg) ^ swz));
            bf16x8 kf1 = *(bf16x8*)((char*)Ks + ((row * 128 + 16 * lg + 64) ^ swz));
            f32x4 z = {};
            z = __builtin_amdgcn_mfma_f32_16x16x32_bf16(qf0, kf0, z, 0, 0, 0);
            z = __builtin_amdgcn_mfma_f32_16x16x32_bf16(qf1, kf1, z, 0, 0, 0);
#pragma unroll
            for (int r = 0; r < 4; r++) x[f][r] = z[r];
        }
        if (kt * 64 + 63 > CARRY + q0 + 16 * w) {
#pragma unroll
            for (int f = 0; f < 4; f++) {
                int sg = kt * 64 + 16 * f + lr;
#pragma unroll
                for (int r = 0; r < 4; r++) {
                    int tg = q0 + 16 * w + 4 * lg + r;
                    if (sg > CARRY + tg) x[f][r] = -1e30f;
                }
            }
        }
        // ==== deferred-max online softmax (no shuffle in common case) ====
        float lm[4];
#pragma unroll
        for (int r = 0; r < 4; r++)
            lm[r] = fmaxf(fmaxf(x[0][r], x[1][r]), fmaxf(x[2][r], x[3][r]));
        bool need = __any(lm[0] > m_run[0] + 8.f) || __any(lm[1] > m_run[1] + 8.f) ||
                    __any(lm[2] > m_run[2] + 8.f) || __any(lm[3] > m_run[3] + 8.f);
        if (need) {
#pragma unroll
            for (int r = 0; r < 4; r++) {
                float mt = lm[r];
                mt = fmaxf(mt, __shfl_xor(mt, 1, 64));
                mt = fmaxf(mt, __shfl_xor(mt, 2, 64));
                mt = fmaxf(mt, __shfl_xor(mt, 4, 64));
                mt = fmaxf(mt, __shfl_xor(mt, 8, 64));
                float mn = fmaxf(m_run[r], mt);
                float fs = __expf(m_run[r] - mn);
                m_run[r] = mn;
                lacc[r] *= fs;
#pragma unroll
                for (int f2 = 0; f2 < 4; f2++) oacc[f2][r] *= fs;
            }
        }
#pragma unroll
        for (int f = 0; f < 4; f++)
#pragma unroll
            for (int r = 0; r < 4; r++)
                x[f][r] = __expf(x[f][r] - m_run[r]);
        // write P (bf16, swizzled); own-wave rows only
#pragma unroll
        for (int f = 0; f < 4; f++) {
#pragma unroll
            for (int r = 0; r < 4; r++) {
                int row = 16 * w + 4 * lg + r;
                int byte = (row * 128 + (16 * f + lr) * 2) ^ ((row & 7) << 4);
                *(u16*)((char*)Ps + byte) = f2b(x[f][r]);
            }
        }
        // PV + row-sum via ones-MFMA (l computed from the same bf16 P)
        {
            int prow = 16 * w + lr;
            int pswz = (prow & 7) << 4;
            bf16x8 pa0 = *(bf16x8*)((char*)Ps + ((prow * 128 + 16 * lg) ^ pswz));
            bf16x8 pa1 = *(bf16x8*)((char*)Ps + ((prow * 128 + 16 * lg + 64) ^ pswz));
            lacc = __builtin_amdgcn_mfma_f32_16x16x32_bf16(pa0, onesf, lacc, 0, 0, 0);
            lacc = __builtin_amdgcn_mfma_f32_16x16x32_bf16(pa1, onesf, lacc, 0, 0, 0);
#pragma unroll
            for (int f2 = 0; f2 < 4; f2++) {
                int d = 16 * f2 + lr;
                int vswz = (d & 7) << 4;
                bf16x8 vf0 = *(bf16x8*)((char*)Vt + ((d * 128 + 16 * lg) ^ vswz));
                bf16x8 vf1 = *(bf16x8*)((char*)Vt + ((d * 128 + 16 * lg + 64) ^ vswz));
                oacc[f2] = __builtin_amdgcn_mfma_f32_16x16x32_bf16(pa0, vf0, oacc[f2], 0, 0, 0);
                oacc[f2] = __builtin_amdgcn_mfma_f32_16x16x32_bf16(pa1, vf1, oacc[f2], 0, 0, 0);
            }
        }
    };

    for (int kt = kt0; kt < kt1; kt += 2) {
        body(kA, vA, kB, vB, kt);
        if (kt + 1 < kt1) body(kB, vB, kA, vA, kt + 1);
    }

    int p = (bh * 2 + qh) * NSPLIT + sp;
    if (lr == 0) {
#pragma unroll
        for (int r = 0; r < 4; r++) {
            int row = 16 * w + 4 * lg + r;
            part_m[(size_t)p * 64 + row] = m_run[r];
            part_l[(size_t)p * 64 + row] = lacc[r];
        }
    }
#pragma unroll
    for (int f2 = 0; f2 < 4; f2++) {
#pragma unroll
        for (int r = 0; r < 4; r++) {
            int row = 16 * w + 4 * lg + r;
            part_acc[(size_t)p * 4096 + row * 64 + 16 * f2 + lr] = oacc[f2][r];
        }
    }
}

// ---- attn combine: merge NSPLIT kv-splits -> ctx bf16 ----
__global__ __launch_bounds__(256) void attn_combine(const float* __restrict__ part_acc,
                                                    const float* __restrict__ part_m,
                                                    const float* __restrict__ part_l,
                                                    u16* __restrict__ ctx) {
    int g = blockIdx.x;
    int bh = g >> 1, qh = g & 1, b = bh >> 4, h = bh & 15;
    int t = threadIdx.x;
    int r = t >> 2, c0 = (t & 3) * 16;
    int p0 = g * NSPLIT;

    float ms[NSPLIT];
    float M = -1e30f;
#pragma unroll
    for (int s = 0; s < NSPLIT; s++) {
        ms[s] = part_m[(size_t)(p0 + s) * 64 + r];
        M = fmaxf(M, ms[s]);
    }
    float wgt[NSPLIT];
    float L = 0.f;
#pragma unroll
    for (int s = 0; s < NSPLIT; s++) {
        wgt[s] = __expf(ms[s] - M);
        L += wgt[s] * part_l[(size_t)(p0 + s) * 64 + r];
    }
    float inv = 1.0f / L;

    size_t grow = (size_t)(b * TLEN + qh * 64 + r) * EMBED + h * HDIM + c0;
#pragma unroll
    for (int j = 0; j < 16; j += 4) {
        float4 a = {0.f, 0.f, 0.f, 0.f};
#pragma unroll
        for (int s = 0; s < NSPLIT; s++) {
            float4 p = *(const float4*)(part_acc + (size_t)(p0 + s) * 4096 + r * 64 + c0 + j);
            a.x += wgt[s] * p.x; a.y += wgt[s] * p.y; a.z += wgt[s] * p.z; a.w += wgt[s] * p.w;
        }
        u16 o0 = f2b(a.x * inv), o1 = f2b(a.y * inv), o2 = f2b(a.z * inv), o3 = f2b(a.w * inv);
        unsigned int u0 = (unsigned int)o0 | ((unsigned int)o1 << 16);
        unsigned int u1 = (unsigned int)o2 | ((unsigned int)o3 << 16);
        uint2 pk = {u0, u1};
        *(uint2*)(ctx + grow + j) = pk;
    }
}

// ---------------- fallback non-split attention (reads k_all/v_all) ----------------
__global__ __launch_bounds__(256) void attn_mfma(const u16* __restrict__ qb,
                                                 const float* __restrict__ k_all,
                                                 const float* __restrict__ v_all,
                                                 u16* __restrict__ ctx) {
    __shared__ u16 Ks[64 * 64];
    __shared__ u16 Vt[64 * 64];
    __shared__ u16 Ps[64 * 64];

    int bh = blockIdx.x, b = bh >> 4, h = bh & 15;
    int q0 = blockIdx.y * 64;
    int tid = threadIdx.x;
    int w = tid >> 6, l = tid & 63, lr = l & 15, lg = l >> 4;

    bf16x8 qf0, qf1;
    {
        const u16* qrow = qb + (size_t)(b * TLEN + q0 + 16 * w + lr) * EMBED + h * HDIM;
        qf0 = *(const bf16x8*)(qrow + 8 * lg);
        qf1 = *(const bf16x8*)(qrow + 8 * lg + 32);
    }
    const float* kb = k_all + (size_t)bh * SEQA * HDIM;
    const float* vb = v_all + (size_t)bh * SEQA * HDIM;

    float m_run[4], l_run[4];
    f32x4 oacc[4] = {};
#pragma unroll
    for (int r = 0; r < 4; r++) { m_run[r] = -1e30f; l_run[r] = 0.f; }

    int nt = (CARRY + q0 + 64) >> 6;
    for (int kt = 0; kt < nt; kt++) {
        __syncthreads();
#pragma unroll
        for (int p = 0; p < 4; p++) {
            int s = (tid >> 4) + 16 * p, c = (tid & 15) * 4;
            float4 kv = *(const float4*)(kb + (size_t)(kt * 64 + s) * HDIM + c);
            u16 t0 = f2b(kv.x), t1 = f2b(kv.y), t2 = f2b(kv.z), t3 = f2b(kv.w);
            unsigned int a = (unsigned int)t0 | ((unsigned int)t1 << 16);
            unsigned int bq = (unsigned int)t2 | ((unsigned int)t3 << 16);
            uint2 pk = {a, bq};
            int byte = (s * 128 + c * 2) ^ ((s & 7) << 4);
            *(uint2*)((char*)Ks + byte) = pk;
        }
        {
            int d = tid & 63;
            u16 tmp[16];
#pragma unroll
            for (int q = 0; q < 16; q++)
                tmp[q] = f2b(vb[(size_t)(kt * 64 + 16 * w + q) * HDIM + d]);
            int b0 = (d * 128 + 32 * w) ^ ((d & 7) << 4);
            int b1 = (d * 128 + 32 * w + 16) ^ ((d & 7) << 4);
            *(bf16x8*)((char*)Vt + b0) = *(bf16x8*)&tmp[0];
            *(bf16x8*)((char*)Vt + b1) = *(bf16x8*)&tmp[8];
        }
        __syncthreads();

        float x[4][4];
#pragma unroll
        for (int f = 0; f < 4; f++) {
            int row = 16 * f + lr;
            int swz = (row & 7) << 4;
            bf16x8 kf0 = *(bf16x8*)((char*)Ks + ((row * 128 + 16 * lg) ^ swz));
            bf16x8 kf1 = *(bf16x8*)((char*)Ks + ((row * 128 + 16 * lg + 64) ^ swz));
            f32x4 z = {};
            z = __builtin_amdgcn_mfma_f32_16x16x32_bf16(qf0, kf0, z, 0, 0, 0);
            z = __builtin_amdgcn_mfma_f32_16x16x32_bf16(qf1, kf1, z, 0, 0, 0);
#pragma unroll
            for (int r = 0; r < 4; r++) x[f][r] = z[r] * 0.125f;
        }
        if (kt * 64 + 63 > CARRY + q0 + 16 * w) {
#pragma unroll
            for (int f = 0; f < 4; f++) {
                int sg = kt * 64 + 16 * f + lr;
#pragma unroll
                for (int r = 0; r < 4; r++) {
                    int tg = q0 + 16 * w + 4 * lg + r;
                    if (sg > CARRY + tg) x[f][r] = -1e30f;
                }
            }
        }
#pragma unroll
        for (int r = 0; r < 4; r++) {
            float mt = fmaxf(fmaxf(x[0][r], x[1][r]), fmaxf(x[2][r], x[3][r]));
            mt = fmaxf(mt, __shfl_xor(mt, 1, 64));
            mt = fmaxf(mt, __shfl_xor(mt, 2, 64));
            mt = fmaxf(mt, __shfl_xor(mt, 4, 64));
            mt = fmaxf(mt, __shfl_xor(mt, 8, 64));
            float mn = fmaxf(m_run[r], mt);
            float fs = __expf(m_run[r] - mn);
            m_run[r] = mn;
            float s = 0.f;
#pragma unroll
            for (int f = 0; f < 4; f++) {
                float p = __expf(x[f][r] - mn);
                x[f][r] = p;
                s += p;
            }
            s += __shfl_xor(s, 1, 64);
            s += __shfl_xor(s, 2, 64);
            s += __shfl_xor(s, 4, 64);
            s += __shfl_xor(s, 8, 64);
            l_run[r] = l_run[r] * fs + s;
#pragma unroll
            for (int f2 = 0; f2 < 4; f2++) oacc[f2][r] *= fs;
        }
#pragma unroll
        for (int f = 0; f < 4; f++) {
#pragma unroll
            for (int r = 0; r < 4; r++) {
                int row = 16 * w + 4 * lg + r;
                int byte = (row * 128 + (16 * f + lr) * 2) ^ ((row & 7) << 4);
                *(u16*)((char*)Ps + byte) = f2b(x[f][r]);
            }
        }
        {
            int prow = 16 * w + lr;
            int pswz = (prow & 7) << 4;
            bf16x8 pa0 = *(bf16x8*)((char*)Ps + ((prow * 128 + 16 * lg) ^ pswz));
            bf16x8 pa1 = *(bf16x8*)((char*)Ps + ((prow * 128 + 16 * lg + 64) ^ pswz));
#pragma unroll
            for (int f2 = 0; f2 < 4; f2++) {
                int d = 16 * f2 + lr;
                int vswz = (d & 7) << 4;
                bf16x8 vf0 = *(bf16x8*)((char*)Vt + ((d * 128 + 16 * lg) ^ vswz));
                bf16x8 vf1 = *(bf16x8*)((char*)Vt + ((d * 128 + 16 * lg + 64) ^ vswz));
                oacc[f2] = __builtin_amdgcn_mfma_f32_16x16x32_bf16(pa0, vf0, oacc[f2], 0, 0, 0);
                oacc[f2] = __builtin_amdgcn_mfma_f32_16x16x32_bf16(pa1, vf1, oacc[f2], 0, 0, 0);
            }
        }
    }
#pragma unroll
    for (int r = 0; r < 4; r++) {
        float inv = 1.0f / l_run[r];
        size_t grow = (size_t)(b * TLEN + q0 + 16 * w + 4 * lg + r) * EMBED + h * HDIM;
#pragma unroll
        for (int f2 = 0; f2 < 4; f2++)
            ctx[grow + 16 * f2 + lr] = f2b(oacc[f2][r] * inv);
    }
}

extern "C" void kernel_launch(void* const* d_in, const int* in_sizes, int n_in,
                              void* d_out, int out_size, void* d_ws, size_t ws_size,
                              hipStream_t stream) {
    const float* hidden = (const float*)d_in[0];
    const float* key_carry = (const float*)d_in[1];
    const float* value_carry = (const float*)d_in[2];
    const float* ln1_s = (const float*)d_in[3];
    const float* ln1_b = (const float*)d_in[4];
    const float* wq = (const float*)d_in[5];
    const float* bq = (const float*)d_in[6];
    const float* wk = (const float*)d_in[7];
    const float* bk = (const float*)d_in[8];
    const float* wv = (const float*)d_in[9];
    const float* bv = (const float*)d_in[10];
    const float* wo = (const float*)d_in[11];
    const float* bo = (const float*)d_in[12];
    const float* ln2_s = (const float*)d_in[13];
    const float* ln2_b = (const float*)d_in[14];
    const float* w1 = (const float*)d_in[15];
    const float* b1 = (const float*)d_in[16];
    const float* w2 = (const float*)d_in[17];
    const float* b2 = (const float*)d_in[18];

    float* out_hidden = (float*)d_out;
    float* k_all = out_hidden + (size_t)MROWS * EMBED;
    float* v_all = k_all + (size_t)BATCH * HEADS * SEQA * HDIM;

    u16* wsu = (u16*)d_ws;
    u16* wqkvT = wsu;                  // [3072][1024]
    u16* woT = wsu + 3145728;          // [1024][1024]
    u16* w1T = wsu + 4194304;          // [4096][1024]
    u16* w2T = wsu + 8388608;          // [1024][4096]
    u16* xb  = wsu + 12582912;
    u16* qbb = wsu + 13631488;
    u16* ctxb = wsu + 14680064;
    u16* fb  = wsu + 15728640;
    u16* h1b = wsu + 16777216;         // [1024][4096]
    float* bias_qkv = (float*)(wsu + 20971520);          // 3072 f32
    float* part = (float*)(wsu + 20977664);
    const size_t nparts = (size_t)256 * NSPLIT;          // (bh*2+qh) x splits
    const size_t need = (size_t)20977664 * 2 +
                        (nparts * 4096 + 2 * nparts * 64) * 4;

    transpose_all<<<dim3(16, 16, 12), 256, 0, stream>>>(wq, wk, wv, wo, w1, w2, bq, bk, bv,
                                                        wqkvT, woT, w1T, w2T, bias_qkv);

    ln_kernel<<<MROWS, 256, 0, stream>>>(hidden, ln1_s, ln1_b, xb);

    if (ws_size >= need) {
        // fused QKV: Q->qbb bf16 (pre-scaled 1/8), K/V -> k_all/v_all rows 4096..4223
        gemm_bf16<5><<<dim3(48, 16), 256, 0, stream>>>(xb, wqkvT, bias_qkv, nullptr,
                                                       k_all, v_all, qbb, 3072, EMBED);
        float* part_acc = part;
        float* part_m = part + nparts * 4096;
        float* part_l = part_m + nparts * 64;
        attn_mfma_split<<<dim3(BATCH * HEADS, 2, NSPLIT), 256, 0, stream>>>(
            qbb, key_carry, value_carry, k_all, v_all, part_acc, part_m, part_l);
        attn_combine<<<256, 256, 0, stream>>>(part_acc, part_m, part_l, ctxb);

        gemm_splitk<<<dim3(16, 16, 2), 256, 0, stream>>>(ctxb, woT, part, EMBED, EMBED, 512);
        combine_ln<<<1024, 256, 0, stream>>>(part, bo, hidden, ln2_s, ln2_b, out_hidden, fb);

        gemm_bf16<3><<<dim3(64, 16), 256, 0, stream>>>(fb, w1T, b1, nullptr, nullptr, nullptr,
                                                       h1b, FFDIM, EMBED);
        gemm_splitk<<<dim3(16, 16, 4), 256, 0, stream>>>(h1b, w2T, part, EMBED, FFDIM, 1024);
        combine_add<4><<<1024, 256, 0, stream>>>(part, b2, out_hidden, out_hidden);
    } else {
        // fallback: non-split schedule with explicit carry copy (unscaled Q path)
        copy_carry_kernel<<<2048, 256, 0, stream>>>(
            (const float4*)key_carry, (const float4*)value_carry,
            (float4*)k_all, (float4*)v_all);
        u16* wqT = wqkvT;
        u16* wkT = wqkvT + 1048576;
        u16* wvT = wqkvT + 2097152;
        gemm_bf16<0><<<dim3(16, 16), 256, 0, stream>>>(xb, wqT, bq, nullptr, nullptr, nullptr,
                                                       qbb, EMBED, EMBED);
        gemm_bf16<1><<<dim3(16, 16), 256, 0, stream>>>(xb, wkT, bk, nullptr, k_all, nullptr,
                                                       nullptr, EMBED, EMBED);
        gemm_bf16<1><<<dim3(16, 16), 256, 0, stream>>>(xb, wvT, bv, nullptr, v_all, nullptr,
                                                       nullptr, EMBED, EMBED);
        attn_mfma<<<dim3(BATCH * HEADS, 2), 256, 0, stream>>>(qbb, k_all, v_all, ctxb);
        gemm_bf16<2><<<dim3(16, 16), 256, 0, stream>>>(ctxb, woT, bo, hidden, out_hidden,
                                                       nullptr, nullptr, EMBED, EMBED);
        ln_kernel<<<MROWS, 256, 0, stream>>>(out_hidden, ln2_s, ln2_b, fb);
        gemm_bf16<3><<<dim3(64, 16), 256, 0, stream>>>(fb, w1T, b1, nullptr, nullptr, nullptr,
                                                       h1b, FFDIM, EMBED);
        gemm_bf16<4><<<dim3(16, 16), 256, 0, stream>>>(h1b, w2T, b2, out_hidden, out_hidden,
                                                       nullptr, nullptr, EMBED, FFDIM);
    }
}

// Round 10
// 235.769 us; speedup vs baseline: 1.3435x; 1.0332x over previous
//
#include <hip/hip_runtime.h>
#include <hip/hip_bf16.h>
#include <math.h>

#define EMBED 1024
#define HEADS 16
#define HDIM 64
#define FFDIM 4096
#define BATCH 8
#define TLEN 128
#define CARRY 4096
#define SEQA (CARRY + TLEN)   // 4224
#define MROWS (BATCH * TLEN)  // 1024
#define NSPLIT 8

typedef __attribute__((ext_vector_type(8))) short bf16x8;
typedef __attribute__((ext_vector_type(4))) float f32x4;
typedef unsigned short u16;

static __device__ __forceinline__ u16 f2b(float v) {
    __hip_bfloat16 h = __float2bfloat16(v);
    return *reinterpret_cast<u16*>(&h);
}

typedef const __attribute__((address_space(1))) unsigned int g_u32;
typedef __attribute__((address_space(3))) unsigned int l_u32;
static __device__ __forceinline__ void gl16(const void* g, void* l) {
    __builtin_amdgcn_global_load_lds((g_u32*)g, (l_u32*)l, 16, 0, 0);
}

// barrier that does NOT drain vmcnt (stores/prefetch loads stay in flight)
static __device__ __forceinline__ void bar_lgkm() {
    asm volatile("s_waitcnt lgkmcnt(0)" ::: "memory");
    __builtin_amdgcn_s_barrier();
    __builtin_amdgcn_sched_barrier(0);
}
static __device__ __forceinline__ void bar_plain() {
    __builtin_amdgcn_sched_barrier(0);
    __builtin_amdgcn_s_barrier();
}

// ---------------- carry copy (fallback path only) ----------------
__global__ void copy_carry_kernel(const float4* __restrict__ kc, const float4* __restrict__ vc,
                                  float4* __restrict__ k_all, float4* __restrict__ v_all) {
    const size_t total = (size_t)BATCH * HEADS * CARRY * HDIM / 4;
    const size_t DH = (size_t)SEQA * HDIM / 4;
    for (size_t e = (size_t)blockIdx.x * blockDim.x + threadIdx.x; e < total;
         e += (size_t)gridDim.x * blockDim.x) {
        size_t bh = e >> 16;
        size_t rem = e & 65535;
        size_t d = bh * DH + rem;
        k_all[d] = kc[e];
        v_all[d] = vc[e];
    }
}

// ---------------- LayerNorm fp32 in -> bf16 out ----------------
__global__ __launch_bounds__(256) void ln_kernel(const float* __restrict__ in,
                                                 const float* __restrict__ scale,
                                                 const float* __restrict__ bias,
                                                 u16* __restrict__ out) {
    int row = blockIdx.x;
    int tid = threadIdx.x;
    const float4* rin = (const float4*)(in + (size_t)row * EMBED);
    float4 v = rin[tid];
    float s = v.x + v.y + v.z + v.w;
    float s2 = v.x * v.x + v.y * v.y + v.z * v.z + v.w * v.w;
    for (int o = 32; o > 0; o >>= 1) {
        s += __shfl_down(s, o, 64);
        s2 += __shfl_down(s2, o, 64);
    }
    __shared__ float ls[8], ls2[8];
    int wid = tid >> 6, lane = tid & 63;
    if (lane == 0) { ls[wid] = s; ls2[wid] = s2; }
    __syncthreads();
    if (tid == 0) {
        float S = 0.f, S2 = 0.f;
        for (int i = 0; i < 4; i++) { S += ls[i]; S2 += ls2[i]; }
        float mu = S * (1.0f / EMBED);
        float var = S2 * (1.0f / EMBED) - mu * mu;
        ls[0] = mu;
        ls2[0] = rsqrtf(var + 1e-5f);
    }
    __syncthreads();
    float mu = ls[0], rstd = ls2[0];
    float sc[4], bi[4], xin[4];
    *(float4*)sc = ((const float4*)scale)[tid];
    *(float4*)bi = ((const float4*)bias)[tid];
    *(float4*)xin = v;
    u16 o0 = f2b((xin[0] - mu) * rstd * sc[0] + bi[0]);
    u16 o1 = f2b((xin[1] - mu) * rstd * sc[1] + bi[1]);
    u16 o2 = f2b((xin[2] - mu) * rstd * sc[2] + bi[2]);
    u16 o3 = f2b((xin[3] - mu) * rstd * sc[3] + bi[3]);
    unsigned int u0 = (unsigned int)o0 | ((unsigned int)o1 << 16);
    unsigned int u1 = (unsigned int)o2 | ((unsigned int)o3 << 16);
    uint2 pk = {u0, u1};
    *(uint2*)(out + (size_t)row * EMBED + tid * 4) = pk;
}

// ---------------- all weight transposes in ONE dispatch ----------------
__global__ __launch_bounds__(256) void transpose_all(const float* __restrict__ wq,
                                                     const float* __restrict__ wk,
                                                     const float* __restrict__ wv,
                                                     const float* __restrict__ wo,
                                                     const float* __restrict__ w1,
                                                     const float* __restrict__ w2,
                                                     const float* __restrict__ bq,
                                                     const float* __restrict__ bk,
                                                     const float* __restrict__ bv,
                                                     u16* __restrict__ wqkvT,
                                                     u16* __restrict__ woT,
                                                     u16* __restrict__ w1T,
                                                     u16* __restrict__ w2T,
                                                     float* __restrict__ bias_qkv) {
    __shared__ float Ls[64][65];
    int z = blockIdx.z;
    int bx = blockIdx.x, by = blockIdx.y;
    const float* W;
    u16* WT;
    int K, N;
    if (z < 4) {
        W = (z == 0) ? wq : (z == 1) ? wk : (z == 2) ? wv : wo;
        WT = (z < 3) ? (wqkvT + (size_t)z * 1024 * 1024) : woT;
        K = 1024; N = 1024;
    } else if (z < 8) {
        W = w1; WT = w1T; K = 1024; N = 4096; bx += (z - 4) * 16;
    } else {
        W = w2; WT = w2T; K = 4096; N = 1024; by += (z - 8) * 16;
    }
    int tid = threadIdx.x;
    if (z == 3 && blockIdx.y == 0 && blockIdx.x < 12) {
        int i = blockIdx.x * 256 + tid;
        bias_qkv[i] = (i < 1024) ? bq[i] : (i < 2048) ? bk[i - 1024] : bv[i - 2048];
    }
    int k0 = by * 64, n0 = bx * 64;
#pragma unroll
    for (int p = 0; p < 4; p++) {
        int r = (tid >> 4) + 16 * p, c = (tid & 15) * 4;
        float4 v = *(const float4*)(W + (size_t)(k0 + r) * N + n0 + c);
        Ls[r][c] = v.x; Ls[r][c + 1] = v.y; Ls[r][c + 2] = v.z; Ls[r][c + 3] = v.w;
    }
    __syncthreads();
#pragma unroll
    for (int p = 0; p < 4; p++) {
        int n = (tid >> 4) + 16 * p, k4 = (tid & 15) * 4;
        u16 o0 = f2b(Ls[k4][n]), o1 = f2b(Ls[k4 + 1][n]);
        u16 o2 = f2b(Ls[k4 + 2][n]), o3 = f2b(Ls[k4 + 3][n]);
        unsigned int a = (unsigned int)o0 | ((unsigned int)o1 << 16);
        unsigned int b = (unsigned int)o2 | ((unsigned int)o3 << 16);
        uint2 pk = {a, b};
        *(uint2*)(WT + (size_t)(n0 + n) * K + k0 + k4) = pk;
    }
}

// ======== shared GEMM staging: global_load_lds(16B) + XOR swizzle ========
static __device__ __forceinline__ void stage2(const u16* __restrict__ Ag,
                                              const u16* __restrict__ Wg,
                                              u16* As, u16* Ws,
                                              int w, int l, int K) {
    int r0 = 16 * w + (l >> 3);
    int scol = ((l & 7) ^ (l >> 3)) * 8;
    char* a0 = (char*)As + w * 2048;
    char* w0 = (char*)Ws + w * 2048;
    gl16(Ag + (size_t)r0 * K + scol, a0);
    gl16(Ag + (size_t)(r0 + 8) * K + scol, a0 + 1024);
    gl16(Wg + (size_t)r0 * K + scol, w0);
    gl16(Wg + (size_t)(r0 + 8) * K + scol, w0 + 1024);
}

// ---------------- bf16 MFMA GEMM: C[M,N] = A[M,K] @ WT[N,K]^T ----------------
// MODE 5 Q-path pre-scales by 1/8 (exact in bf16) so attention skips it.
template <int MODE>
__global__ __launch_bounds__(256) void gemm_bf16(const u16* __restrict__ A,
                                                 const u16* __restrict__ WT,
                                                 const float* __restrict__ bias,
                                                 const float* __restrict__ resid,
                                                 float* __restrict__ outf,
                                                 float* __restrict__ outf2,
                                                 u16* __restrict__ outb, int N, int K) {
    __shared__ u16 As[64 * 64];
    __shared__ u16 Ws[64 * 64];
    int tid = threadIdx.x;
    int m0 = blockIdx.y * 64, n0 = blockIdx.x * 64;
    int w = tid >> 6, l = tid & 63, lr = l & 15, lg = l >> 4;
    f32x4 acc[4] = {};

    const u16* Ag = A + (size_t)m0 * K;
    const u16* Wg = WT + (size_t)n0 * K;

    for (int k0 = 0; k0 < K; k0 += 64) {
        __syncthreads();
        stage2(Ag + k0, Wg + k0, As, Ws, w, l, K);
        __syncthreads();
#pragma unroll
        for (int ks = 0; ks < 2; ks++) {
            int abyte = ((16 * w + lr) * 128 + lg * 16 + ks * 64) ^ ((lr & 7) << 4);
            bf16x8 af = *(bf16x8*)((char*)As + abyte);
#pragma unroll
            for (int f = 0; f < 4; f++) {
                int bbyte = ((16 * f + lr) * 128 + lg * 16 + ks * 64) ^ ((lr & 7) << 4);
                bf16x8 bfr = *(bf16x8*)((char*)Ws + bbyte);
                acc[f] = __builtin_amdgcn_mfma_f32_16x16x32_bf16(af, bfr, acc[f], 0, 0, 0);
            }
        }
    }

    int gr0 = m0 + 16 * w + 4 * lg;
#pragma unroll
    for (int f = 0; f < 4; f++) {
        int gc = n0 + 16 * f + lr;
        float bv = bias[gc];
#pragma unroll
        for (int r = 0; r < 4; r++) {
            int gm = gr0 + r;
            float v = acc[f][r] + bv;
            if (MODE == 3) v = 0.5f * v * (1.0f + erff(v * 0.70710678118654752f));
            if (MODE == 2 || MODE == 4) v += resid[(size_t)gm * EMBED + gc];
            if (MODE == 0 || MODE == 3) {
                outb[(size_t)gm * N + gc] = f2b(v);
            } else if (MODE == 1) {
                int b_ = gm >> 7, t_ = gm & 127, h_ = gc >> 6, d_ = gc & 63;
                outf[(((size_t)(b_ * HEADS + h_)) * SEQA + CARRY + t_) * HDIM + d_] = v;
            } else if (MODE == 5) {
                if (gc < 1024) {
                    outb[(size_t)gm * EMBED + gc] = f2b(v * 0.125f); // pre-scaled Q
                } else {
                    int which = gc >> 10;
                    int gc2 = gc & 1023;
                    int b_ = gm >> 7, t_ = gm & 127, h_ = gc2 >> 6, d_ = gc2 & 63;
                    float* dst = (which == 1) ? outf : outf2;
                    dst[(((size_t)(b_ * HEADS + h_)) * SEQA + CARRY + t_) * HDIM + d_] = v;
                }
            } else {
                outf[(size_t)gm * EMBED + gc] = v;
            }
        }
    }
}

// ---------------- split-K GEMM -> fp32 partials ----------------
__global__ __launch_bounds__(256) void gemm_splitk(const u16* __restrict__ A,
                                                   const u16* __restrict__ WT,
                                                   float* __restrict__ part,
                                                   int N, int Ktot, int Klen) {
    __shared__ u16 As[64 * 64];
    __shared__ u16 Ws[64 * 64];
    int tid = threadIdx.x;
    int m0 = blockIdx.y * 64, n0 = blockIdx.x * 64;
    int k0s = blockIdx.z * Klen;
    int w = tid >> 6, l = tid & 63, lr = l & 15, lg = l >> 4;
    f32x4 acc[4] = {};

    const u16* Ag = A + (size_t)m0 * Ktot;
    const u16* Wg = WT + (size_t)n0 * Ktot;

    for (int k0 = k0s; k0 < k0s + Klen; k0 += 64) {
        __syncthreads();
        stage2(Ag + k0, Wg + k0, As, Ws, w, l, Ktot);
        __syncthreads();
#pragma unroll
        for (int ks = 0; ks < 2; ks++) {
            int abyte = ((16 * w + lr) * 128 + lg * 16 + ks * 64) ^ ((lr & 7) << 4);
            bf16x8 af = *(bf16x8*)((char*)As + abyte);
#pragma unroll
            for (int f = 0; f < 4; f++) {
                int bbyte = ((16 * f + lr) * 128 + lg * 16 + ks * 64) ^ ((lr & 7) << 4);
                bf16x8 bfr = *(bf16x8*)((char*)Ws + bbyte);
                acc[f] = __builtin_amdgcn_mfma_f32_16x16x32_bf16(af, bfr, acc[f], 0, 0, 0);
            }
        }
    }

    float* pbase = part + (size_t)blockIdx.z * MROWS * N;
    int gr0 = m0 + 16 * w + 4 * lg;
#pragma unroll
    for (int f = 0; f < 4; f++) {
        int gc = n0 + 16 * f + lr;
#pragma unroll
        for (int r = 0; r < 4; r++)
            pbase[(size_t)(gr0 + r) * N + gc] = acc[f][r];
    }
}

// ---- combine (final): out = resid + bias + sum_s part[s] ----
template <int NS>
__global__ __launch_bounds__(256) void combine_add(const float* __restrict__ part,
                                                   const float* __restrict__ bias,
                                                   const float* __restrict__ resid,
                                                   float* __restrict__ out) {
    size_t e = ((size_t)blockIdx.x * 256 + threadIdx.x) * 4;
    int n0 = (int)(e & 1023);
    float4 v = *(const float4*)(resid + e);
    float4 b = *(const float4*)(bias + n0);
    v.x += b.x; v.y += b.y; v.z += b.z; v.w += b.w;
#pragma unroll
    for (int s = 0; s < NS; s++) {
        float4 p = *(const float4*)(part + (size_t)s * MROWS * EMBED + e);
        v.x += p.x; v.y += p.y; v.z += p.z; v.w += p.w;
    }
    *(float4*)(out + e) = v;
}

// ---- combine proj + LN2 fused ----
__global__ __launch_bounds__(256) void combine_ln(const float* __restrict__ part,
                                                  const float* __restrict__ bias,
                                                  const float* __restrict__ resid,
                                                  const float* __restrict__ ln_s,
                                                  const float* __restrict__ ln_b,
                                                  float* __restrict__ out,
                                                  u16* __restrict__ outb) {
    int row = blockIdx.x, tid = threadIdx.x;
    size_t base = (size_t)row * EMBED + tid * 4;
    float4 v = *(const float4*)(resid + base);
    float4 b = *(const float4*)(bias + tid * 4);
    v.x += b.x; v.y += b.y; v.z += b.z; v.w += b.w;
#pragma unroll
    for (int s = 0; s < 2; s++) {
        float4 p = *(const float4*)(part + (size_t)s * MROWS * EMBED + base);
        v.x += p.x; v.y += p.y; v.z += p.z; v.w += p.w;
    }
    *(float4*)(out + base) = v;

    float s1 = v.x + v.y + v.z + v.w;
    float s2 = v.x * v.x + v.y * v.y + v.z * v.z + v.w * v.w;
    for (int o = 32; o > 0; o >>= 1) {
        s1 += __shfl_down(s1, o, 64);
        s2 += __shfl_down(s2, o, 64);
    }
    __shared__ float ls[8], ls2[8];
    int wid = tid >> 6, lane = tid & 63;
    if (lane == 0) { ls[wid] = s1; ls2[wid] = s2; }
    __syncthreads();
    if (tid == 0) {
        float S = 0.f, S2 = 0.f;
        for (int i = 0; i < 4; i++) { S += ls[i]; S2 += ls2[i]; }
        float mu = S * (1.0f / EMBED);
        float var = S2 * (1.0f / EMBED) - mu * mu;
        ls[0] = mu;
        ls2[0] = rsqrtf(var + 1e-5f);
    }
    __syncthreads();
    float mu = ls[0], rstd = ls2[0];
    float sc[4], bi[4];
    *(float4*)sc = ((const float4*)ln_s)[tid];
    *(float4*)bi = ((const float4*)ln_b)[tid];
    u16 o0 = f2b((v.x - mu) * rstd * sc[0] + bi[0]);
    u16 o1 = f2b((v.y - mu) * rstd * sc[1] + bi[1]);
    u16 o2 = f2b((v.z - mu) * rstd * sc[2] + bi[2]);
    u16 o3 = f2b((v.w - mu) * rstd * sc[3] + bi[3]);
    unsigned int u0 = (unsigned int)o0 | ((unsigned int)o1 << 16);
    unsigned int u1 = (unsigned int)o2 | ((unsigned int)o3 << 16);
    uint2 pk = {u0, u1};
    *(uint2*)(outb + base) = pk;
}

// ---------------- MFMA flash attention v6: dual-qh dedup ----------------
// grid (B*H, NSPLIT), 256 threads / 4 waves. One block owns BOTH q-halves for
// its (bh, kv-split): carry tile read ONCE, staged ONCE, used for 2x compute,
// written through ONCE. Single staging register set (stage->store->reload in
// program order; VMEM/DS latch operands at issue). Defer-max softmax +
// ones-MFMA row-sum (R9). Raw barriers, vmcnt never drained in-loop.
__global__ __launch_bounds__(256) void attn_mfma_split(const u16* __restrict__ qb,
                                                       const float* __restrict__ kc,
                                                       const float* __restrict__ vc,
                                                       float* __restrict__ k_all,
                                                       float* __restrict__ v_all,
                                                       float* __restrict__ part_acc,
                                                       float* __restrict__ part_m,
                                                       float* __restrict__ part_l) {
    __shared__ u16 Ks[64 * 64];
    __shared__ u16 Vt[64 * 64];
    __shared__ u16 Ps[64 * 64];   // reused sequentially by qh=0 then qh=1 (wave-local rows)

    int bh = blockIdx.x, b = bh >> 4, h = bh & 15;
    int sp = blockIdx.y;
    int tid = threadIdx.x;
    int w = tid >> 6, l = tid & 63, lr = l & 15, lg = l >> 4;

    // Q fragments for both q-halves (pre-scaled by 1/8 upstream)
    bf16x8 qf[2][2];
#pragma unroll
    for (int qh = 0; qh < 2; qh++) {
        const u16* qrow = qb + (size_t)(b * TLEN + qh * 64 + 16 * w + lr) * EMBED + h * HDIM;
        qf[qh][0] = *(const bf16x8*)(qrow + 8 * lg);
        qf[qh][1] = *(const bf16x8*)(qrow + 8 * lg + 32);
    }

    bf16x8 onesf;
#pragma unroll
    for (int j = 0; j < 8; j++) onesf[j] = (short)0x3F80;

    const float* kcb = kc + (size_t)bh * CARRY * HDIM;
    const float* vcb = vc + (size_t)bh * CARRY * HDIM;
    const float* kb = k_all + (size_t)bh * SEQA * HDIM;
    const float* vb = v_all + (size_t)bh * SEQA * HDIM;
    float* kwr = k_all + (size_t)bh * SEQA * HDIM;
    float* vwr = v_all + (size_t)bh * SEQA * HDIM;

    float m_run[2][4];
    f32x4 lacc[2] = {};
    f32x4 oacc[2][4] = {};
#pragma unroll
    for (int qh = 0; qh < 2; qh++)
#pragma unroll
        for (int r = 0; r < 4; r++) m_run[qh][r] = -1e30f;

    const int nt = SEQA / 64;                   // 66 (qh=0's tile 65 fully masked -> zeros)
    const int tps = (nt + NSPLIT - 1) / NSPLIT; // 9
    int kt0 = sp * tps;
    int kt1 = min(kt0 + tps, nt);

    // staging thread geometry (as R9)
    int krow = tid >> 4;          // +16p -> K rows
    int vrow4 = (tid >> 4) * 4;   // +p   -> V rows (4 consecutive)
    int col = (tid & 15) * 4;     // fp32 col

    float4 kr[4], vr[4];

    // prologue: load first tile
    {
        bool cn = kt0 < 64;
        const float* ksrc = cn ? kcb : kb;
        const float* vsrc = cn ? vcb : vb;
#pragma unroll
        for (int p = 0; p < 4; p++)
            kr[p] = *(const float4*)(ksrc + (size_t)(kt0 * 64 + krow + 16 * p) * HDIM + col);
#pragma unroll
        for (int p = 0; p < 4; p++)
            vr[p] = *(const float4*)(vsrc + (size_t)(kt0 * 64 + vrow4 + p) * HDIM + col);
    }

    for (int kt = kt0; kt < kt1; kt++) {
        bool carry_t = kt < 64;
        bar_plain(); // previous tile's PV reads of Ks/Vt done
        // K -> LDS (bf16, swizzled) from kr
#pragma unroll
        for (int p = 0; p < 4; p++) {
            int s = krow + 16 * p;
            u16 t0 = f2b(kr[p].x), t1 = f2b(kr[p].y), t2 = f2b(kr[p].z), t3 = f2b(kr[p].w);
            unsigned int a = (unsigned int)t0 | ((unsigned int)t1 << 16);
            unsigned int bq = (unsigned int)t2 | ((unsigned int)t3 << 16);
            uint2 pk = {a, bq};
            *(uint2*)((char*)Ks + ((s * 128 + col * 2) ^ ((s & 7) << 4))) = pk;
        }
        // V -> LDS transposed (4x4 register transpose) from vr
#pragma unroll
        for (int i = 0; i < 4; i++) {
            int d = col + i;
            u16 e0 = f2b(((const float*)&vr[0])[i]);
            u16 e1 = f2b(((const float*)&vr[1])[i]);
            u16 e2 = f2b(((const float*)&vr[2])[i]);
            u16 e3 = f2b(((const float*)&vr[3])[i]);
            unsigned int a = (unsigned int)e0 | ((unsigned int)e1 << 16);
            unsigned int bq = (unsigned int)e2 | ((unsigned int)e3 << 16);
            uint2 pk = {a, bq};
            *(uint2*)((char*)Vt + ((d * 128 + vrow4 * 2) ^ ((d & 7) << 4))) = pk;
        }
        // carry write-through (exactly-once; stores fly, never waited in-loop)
        if (carry_t) {
#pragma unroll
            for (int p = 0; p < 4; p++)
                *(float4*)(kwr + (size_t)(kt * 64 + krow + 16 * p) * HDIM + col) = kr[p];
#pragma unroll
            for (int p = 0; p < 4; p++)
                *(float4*)(vwr + (size_t)(kt * 64 + vrow4 + p) * HDIM + col) = vr[p];
        }
        // reload SAME registers with next tile (in flight across this tile's compute)
        int ktn = kt + 1;
        if (ktn < kt1) {
            bool cn = ktn < 64;
            const float* ksrc = cn ? kcb : kb;
            const float* vsrc = cn ? vcb : vb;
#pragma unroll
            for (int p = 0; p < 4; p++)
                kr[p] = *(const float4*)(ksrc + (size_t)(ktn * 64 + krow + 16 * p) * HDIM + col);
#pragma unroll
            for (int p = 0; p < 4; p++)
                vr[p] = *(const float4*)(vsrc + (size_t)(ktn * 64 + vrow4 + p) * HDIM + col);
        }
        bar_lgkm(); // staging visible to all waves (vmcnt NOT drained)

        // ==== compute both q-halves from the single staged tile ====
#pragma unroll
        for (int qh = 0; qh < 2; qh++) {
            int q0 = qh * 64;
            float x[4][4];
#pragma unroll
            for (int f = 0; f < 4; f++) {
                int row = 16 * f + lr;
                int swz = (row & 7) << 4;
                bf16x8 kf0 = *(bf16x8*)((char*)Ks + ((row * 128 + 16 * lg) ^ swz));
                bf16x8 kf1 = *(bf16x8*)((char*)Ks + ((row * 128 + 16 * lg + 64) ^ swz));
                f32x4 z = {};
                z = __builtin_amdgcn_mfma_f32_16x16x32_bf16(qf[qh][0], kf0, z, 0, 0, 0);
                z = __builtin_amdgcn_mfma_f32_16x16x32_bf16(qf[qh][1], kf1, z, 0, 0, 0);
#pragma unroll
                for (int r = 0; r < 4; r++) x[f][r] = z[r];
            }
            if (kt * 64 + 63 > CARRY + q0 + 16 * w) {
#pragma unroll
                for (int f = 0; f < 4; f++) {
                    int sg = kt * 64 + 16 * f + lr;
#pragma unroll
                    for (int r = 0; r < 4; r++) {
                        int tg = q0 + 16 * w + 4 * lg + r;
                        if (sg > CARRY + tg) x[f][r] = -1e30f;
                    }
                }
            }
            // deferred-max online softmax
            float lm[4];
#pragma unroll
            for (int r = 0; r < 4; r++)
                lm[r] = fmaxf(fmaxf(x[0][r], x[1][r]), fmaxf(x[2][r], x[3][r]));
            bool need = __any(lm[0] > m_run[qh][0] + 8.f) || __any(lm[1] > m_run[qh][1] + 8.f) ||
                        __any(lm[2] > m_run[qh][2] + 8.f) || __any(lm[3] > m_run[qh][3] + 8.f);
            if (need) {
#pragma unroll
                for (int r = 0; r < 4; r++) {
                    float mt = lm[r];
                    mt = fmaxf(mt, __shfl_xor(mt, 1, 64));
                    mt = fmaxf(mt, __shfl_xor(mt, 2, 64));
                    mt = fmaxf(mt, __shfl_xor(mt, 4, 64));
                    mt = fmaxf(mt, __shfl_xor(mt, 8, 64));
                    float mn = fmaxf(m_run[qh][r], mt);
                    float fs = __expf(m_run[qh][r] - mn);
                    m_run[qh][r] = mn;
                    lacc[qh][r] *= fs;
#pragma unroll
                    for (int f2 = 0; f2 < 4; f2++) oacc[qh][f2][r] *= fs;
                }
            }
#pragma unroll
            for (int f = 0; f < 4; f++)
#pragma unroll
                for (int r = 0; r < 4; r++)
                    x[f][r] = __expf(x[f][r] - m_run[qh][r]);
            // write P (bf16, swizzled); own-wave rows only (no barrier needed)
#pragma unroll
            for (int f = 0; f < 4; f++) {
#pragma unroll
                for (int r = 0; r < 4; r++) {
                    int row = 16 * w + 4 * lg + r;
                    int byte = (row * 128 + (16 * f + lr) * 2) ^ ((row & 7) << 4);
                    *(u16*)((char*)Ps + byte) = f2b(x[f][r]);
                }
            }
            // PV + row-sum via ones-MFMA
            {
                int prow = 16 * w + lr;
                int pswz = (prow & 7) << 4;
                bf16x8 pa0 = *(bf16x8*)((char*)Ps + ((prow * 128 + 16 * lg) ^ pswz));
                bf16x8 pa1 = *(bf16x8*)((char*)Ps + ((prow * 128 + 16 * lg + 64) ^ pswz));
                lacc[qh] = __builtin_amdgcn_mfma_f32_16x16x32_bf16(pa0, onesf, lacc[qh], 0, 0, 0);
                lacc[qh] = __builtin_amdgcn_mfma_f32_16x16x32_bf16(pa1, onesf, lacc[qh], 0, 0, 0);
#pragma unroll
                for (int f2 = 0; f2 < 4; f2++) {
                    int d = 16 * f2 + lr;
                    int vswz = (d & 7) << 4;
                    bf16x8 vf0 = *(bf16x8*)((char*)Vt + ((d * 128 + 16 * lg) ^ vswz));
                    bf16x8 vf1 = *(bf16x8*)((char*)Vt + ((d * 128 + 16 * lg + 64) ^ vswz));
                    oacc[qh][f2] = __builtin_amdgcn_mfma_f32_16x16x32_bf16(pa0, vf0, oacc[qh][f2], 0, 0, 0);
                    oacc[qh][f2] = __builtin_amdgcn_mfma_f32_16x16x32_bf16(pa1, vf1, oacc[qh][f2], 0, 0, 0);
                }
            }
        }
    }

    // partials: p = bh*NSPLIT + sp ; row = qh*64 + 16w + 4lg + r (128 rows)
    int p = bh * NSPLIT + sp;
#pragma unroll
    for (int qh = 0; qh < 2; qh++) {
        if (lr == 0) {
#pragma unroll
            for (int r = 0; r < 4; r++) {
                int row = qh * 64 + 16 * w + 4 * lg + r;
                part_m[(size_t)p * 128 + row] = m_run[qh][r];
                part_l[(size_t)p * 128 + row] = lacc[qh][r];
            }
        }
#pragma unroll
        for (int f2 = 0; f2 < 4; f2++) {
#pragma unroll
            for (int r = 0; r < 4; r++) {
                int row = qh * 64 + 16 * w + 4 * lg + r;
                part_acc[(size_t)p * 8192 + row * 64 + 16 * f2 + lr] = oacc[qh][f2][r];
            }
        }
    }
}

// ---- attn combine: merge NSPLIT kv-splits -> ctx bf16 ----
__global__ __launch_bounds__(256) void attn_combine(const float* __restrict__ part_acc,
                                                    const float* __restrict__ part_m,
                                                    const float* __restrict__ part_l,
                                                    u16* __restrict__ ctx) {
    int g = blockIdx.x;                 // 256 blocks: bh*2 + qh
    int bh = g >> 1, qh = g & 1, b = bh >> 4, h = bh & 15;
    int t = threadIdx.x;
    int r = t >> 2, c0 = (t & 3) * 16;
    int row = qh * 64 + r;
    int p0 = bh * NSPLIT;

    float ms[NSPLIT];
    float M = -1e30f;
#pragma unroll
    for (int s = 0; s < NSPLIT; s++) {
        ms[s] = part_m[(size_t)(p0 + s) * 128 + row];
        M = fmaxf(M, ms[s]);
    }
    float wgt[NSPLIT];
    float L = 0.f;
#pragma unroll
    for (int s = 0; s < NSPLIT; s++) {
        wgt[s] = __expf(ms[s] - M);
        L += wgt[s] * part_l[(size_t)(p0 + s) * 128 + row];
    }
    float inv = 1.0f / L;

    size_t grow = (size_t)(b * TLEN + row) * EMBED + h * HDIM + c0;
#pragma unroll
    for (int j = 0; j < 16; j += 4) {
        float4 a = {0.f, 0.f, 0.f, 0.f};
#pragma unroll
        for (int s = 0; s < NSPLIT; s++) {
            float4 p = *(const float4*)(part_acc + (size_t)(p0 + s) * 8192 + row * 64 + c0 + j);
            a.x += wgt[s] * p.x; a.y += wgt[s] * p.y; a.z += wgt[s] * p.z; a.w += wgt[s] * p.w;
        }
        u16 o0 = f2b(a.x * inv), o1 = f2b(a.y * inv), o2 = f2b(a.z * inv), o3 = f2b(a.w * inv);
        unsigned int u0 = (unsigned int)o0 | ((unsigned int)o1 << 16);
        unsigned int u1 = (unsigned int)o2 | ((unsigned int)o3 << 16);
        uint2 pk = {u0, u1};
        *(uint2*)(ctx + grow + j) = pk;
    }
}

// ---------------- fallback non-split attention (reads k_all/v_all) ----------------
__global__ __launch_bounds__(256) void attn_mfma(const u16* __restrict__ qb,
                                                 const float* __restrict__ k_all,
                                                 const float* __restrict__ v_all,
                                                 u16* __restrict__ ctx) {
    __shared__ u16 Ks[64 * 64];
    __shared__ u16 Vt[64 * 64];
    __shared__ u16 Ps[64 * 64];

    int bh = blockIdx.x, b = bh >> 4, h = bh & 15;
    int q0 = blockIdx.y * 64;
    int tid = threadIdx.x;
    int w = tid >> 6, l = tid & 63, lr = l & 15, lg = l >> 4;

    bf16x8 qf0, qf1;
    {
        const u16* qrow = qb + (size_t)(b * TLEN + q0 + 16 * w + lr) * EMBED + h * HDIM;
        qf0 = *(const bf16x8*)(qrow + 8 * lg);
        qf1 = *(const bf16x8*)(qrow + 8 * lg + 32);
    }
    const float* kb = k_all + (size_t)bh * SEQA * HDIM;
    const float* vb = v_all + (size_t)bh * SEQA * HDIM;

    float m_run[4], l_run[4];
    f32x4 oacc[4] = {};
#pragma unroll
    for (int r = 0; r < 4; r++) { m_run[r] = -1e30f; l_run[r] = 0.f; }

    int nt = (CARRY + q0 + 64) >> 6;
    for (int kt = 0; kt < nt; kt++) {
        __syncthreads();
#pragma unroll
        for (int p = 0; p < 4; p++) {
            int s = (tid >> 4) + 16 * p, c = (tid & 15) * 4;
            float4 kv = *(const float4*)(kb + (size_t)(kt * 64 + s) * HDIM + c);
            u16 t0 = f2b(kv.x), t1 = f2b(kv.y), t2 = f2b(kv.z), t3 = f2b(kv.w);
            unsigned int a = (unsigned int)t0 | ((unsigned int)t1 << 16);
            unsigned int bq = (unsigned int)t2 | ((unsigned int)t3 << 16);
            uint2 pk = {a, bq};
            int byte = (s * 128 + c * 2) ^ ((s & 7) << 4);
            *(uint2*)((char*)Ks + byte) = pk;
        }
        {
            int d = tid & 63;
            u16 tmp[16];
#pragma unroll
            for (int q = 0; q < 16; q++)
                tmp[q] = f2b(vb[(size_t)(kt * 64 + 16 * w + q) * HDIM + d]);
            int b0 = (d * 128 + 32 * w) ^ ((d & 7) << 4);
            int b1 = (d * 128 + 32 * w + 16) ^ ((d & 7) << 4);
            *(bf16x8*)((char*)Vt + b0) = *(bf16x8*)&tmp[0];
            *(bf16x8*)((char*)Vt + b1) = *(bf16x8*)&tmp[8];
        }
        __syncthreads();

        float x[4][4];
#pragma unroll
        for (int f = 0; f < 4; f++) {
            int row = 16 * f + lr;
            int swz = (row & 7) << 4;
            bf16x8 kf0 = *(bf16x8*)((char*)Ks + ((row * 128 + 16 * lg) ^ swz));
            bf16x8 kf1 = *(bf16x8*)((char*)Ks + ((row * 128 + 16 * lg + 64) ^ swz));
            f32x4 z = {};
            z = __builtin_amdgcn_mfma_f32_16x16x32_bf16(qf0, kf0, z, 0, 0, 0);
            z = __builtin_amdgcn_mfma_f32_16x16x32_bf16(qf1, kf1, z, 0, 0, 0);
#pragma unroll
            for (int r = 0; r < 4; r++) x[f][r] = z[r] * 0.125f;
        }
        if (kt * 64 + 63 > CARRY + q0 + 16 * w) {
#pragma unroll
            for (int f = 0; f < 4; f++) {
                int sg = kt * 64 + 16 * f + lr;
#pragma unroll
                for (int r = 0; r < 4; r++) {
                    int tg = q0 + 16 * w + 4 * lg + r;
                    if (sg > CARRY + tg) x[f][r] = -1e30f;
                }
            }
        }
#pragma unroll
        for (int r = 0; r < 4; r++) {
            float mt = fmaxf(fmaxf(x[0][r], x[1][r]), fmaxf(x[2][r], x[3][r]));
            mt = fmaxf(mt, __shfl_xor(mt, 1, 64));
            mt = fmaxf(mt, __shfl_xor(mt, 2, 64));
            mt = fmaxf(mt, __shfl_xor(mt, 4, 64));
            mt = fmaxf(mt, __shfl_xor(mt, 8, 64));
            float mn = fmaxf(m_run[r], mt);
            float fs = __expf(m_run[r] - mn);
            m_run[r] = mn;
            float s = 0.f;
#pragma unroll
            for (int f = 0; f < 4; f++) {
                float p = __expf(x[f][r] - mn);
                x[f][r] = p;
                s += p;
            }
            s += __shfl_xor(s, 1, 64);
            s += __shfl_xor(s, 2, 64);
            s += __shfl_xor(s, 4, 64);
            s += __shfl_xor(s, 8, 64);
            l_run[r] = l_run[r] * fs + s;
#pragma unroll
            for (int f2 = 0; f2 < 4; f2++) oacc[f2][r] *= fs;
        }
#pragma unroll
        for (int f = 0; f < 4; f++) {
#pragma unroll
            for (int r = 0; r < 4; r++) {
                int row = 16 * w + 4 * lg + r;
                int byte = (row * 128 + (16 * f + lr) * 2) ^ ((row & 7) << 4);
                *(u16*)((char*)Ps + byte) = f2b(x[f][r]);
            }
        }
        {
            int prow = 16 * w + lr;
            int pswz = (prow & 7) << 4;
            bf16x8 pa0 = *(bf16x8*)((char*)Ps + ((prow * 128 + 16 * lg) ^ pswz));
            bf16x8 pa1 = *(bf16x8*)((char*)Ps + ((prow * 128 + 16 * lg + 64) ^ pswz));
#pragma unroll
            for (int f2 = 0; f2 < 4; f2++) {
                int d = 16 * f2 + lr;
                int vswz = (d & 7) << 4;
                bf16x8 vf0 = *(bf16x8*)((char*)Vt + ((d * 128 + 16 * lg) ^ vswz));
                bf16x8 vf1 = *(bf16x8*)((char*)Vt + ((d * 128 + 16 * lg + 64) ^ vswz));
                oacc[f2] = __builtin_amdgcn_mfma_f32_16x16x32_bf16(pa0, vf0, oacc[f2], 0, 0, 0);
                oacc[f2] = __builtin_amdgcn_mfma_f32_16x16x32_bf16(pa1, vf1, oacc[f2], 0, 0, 0);
            }
        }
    }
#pragma unroll
    for (int r = 0; r < 4; r++) {
        float inv = 1.0f / l_run[r];
        size_t grow = (size_t)(b * TLEN + q0 + 16 * w + 4 * lg + r) * EMBED + h * HDIM;
#pragma unroll
        for (int f2 = 0; f2 < 4; f2++)
            ctx[grow + 16 * f2 + lr] = f2b(oacc[f2][r] * inv);
    }
}

extern "C" void kernel_launch(void* const* d_in, const int* in_sizes, int n_in,
                              void* d_out, int out_size, void* d_ws, size_t ws_size,
                              hipStream_t stream) {
    const float* hidden = (const float*)d_in[0];
    const float* key_carry = (const float*)d_in[1];
    const float* value_carry = (const float*)d_in[2];
    const float* ln1_s = (const float*)d_in[3];
    const float* ln1_b = (const float*)d_in[4];
    const float* wq = (const float*)d_in[5];
    const float* bq = (const float*)d_in[6];
    const float* wk = (const float*)d_in[7];
    const float* bk = (const float*)d_in[8];
    const float* wv = (const float*)d_in[9];
    const float* bv = (const float*)d_in[10];
    const float* wo = (const float*)d_in[11];
    const float* bo = (const float*)d_in[12];
    const float* ln2_s = (const float*)d_in[13];
    const float* ln2_b = (const float*)d_in[14];
    const float* w1 = (const float*)d_in[15];
    const float* b1 = (const float*)d_in[16];
    const float* w2 = (const float*)d_in[17];
    const float* b2 = (const float*)d_in[18];

    float* out_hidden = (float*)d_out;
    float* k_all = out_hidden + (size_t)MROWS * EMBED;
    float* v_all = k_all + (size_t)BATCH * HEADS * SEQA * HDIM;

    u16* wsu = (u16*)d_ws;
    u16* wqkvT = wsu;                  // [3072][1024]
    u16* woT = wsu + 3145728;          // [1024][1024]
    u16* w1T = wsu + 4194304;          // [4096][1024]
    u16* w2T = wsu + 8388608;          // [1024][4096]
    u16* xb  = wsu + 12582912;
    u16* qbb = wsu + 13631488;
    u16* ctxb = wsu + 14680064;
    u16* fb  = wsu + 15728640;
    u16* h1b = wsu + 16777216;         // [1024][4096]
    float* bias_qkv = (float*)(wsu + 20971520);          // 3072 f32
    float* part = (float*)(wsu + 20977664);
    const size_t nparts = (size_t)128 * NSPLIT;          // bh x splits
    const size_t need = (size_t)20977664 * 2 +
                        (nparts * 8192 + 2 * nparts * 128) * 4;

    transpose_all<<<dim3(16, 16, 12), 256, 0, stream>>>(wq, wk, wv, wo, w1, w2, bq, bk, bv,
                                                        wqkvT, woT, w1T, w2T, bias_qkv);

    ln_kernel<<<MROWS, 256, 0, stream>>>(hidden, ln1_s, ln1_b, xb);

    if (ws_size >= need) {
        // fused QKV: Q->qbb bf16 (pre-scaled 1/8), K/V -> k_all/v_all rows 4096..4223
        gemm_bf16<5><<<dim3(48, 16), 256, 0, stream>>>(xb, wqkvT, bias_qkv, nullptr,
                                                       k_all, v_all, qbb, 3072, EMBED);
        float* part_acc = part;
        float* part_m = part + nparts * 8192;
        float* part_l = part_m + nparts * 128;
        attn_mfma_split<<<dim3(BATCH * HEADS, NSPLIT), 256, 0, stream>>>(
            qbb, key_carry, value_carry, k_all, v_all, part_acc, part_m, part_l);
        attn_combine<<<256, 256, 0, stream>>>(part_acc, part_m, part_l, ctxb);

        gemm_splitk<<<dim3(16, 16, 2), 256, 0, stream>>>(ctxb, woT, part, EMBED, EMBED, 512);
        combine_ln<<<1024, 256, 0, stream>>>(part, bo, hidden, ln2_s, ln2_b, out_hidden, fb);

        gemm_bf16<3><<<dim3(64, 16), 256, 0, stream>>>(fb, w1T, b1, nullptr, nullptr, nullptr,
                                                       h1b, FFDIM, EMBED);
        gemm_splitk<<<dim3(16, 16, 4), 256, 0, stream>>>(h1b, w2T, part, EMBED, FFDIM, 1024);
        combine_add<4><<<1024, 256, 0, stream>>>(part, b2, out_hidden, out_hidden);
    } else {
        // fallback: non-split schedule with explicit carry copy (unscaled Q path)
        copy_carry_kernel<<<2048, 256, 0, stream>>>(
            (const float4*)key_carry, (const float4*)value_carry,
            (float4*)k_all, (float4*)v_all);
        u16* wqT = wqkvT;
        u16* wkT = wqkvT + 1048576;
        u16* wvT = wqkvT + 2097152;
        gemm_bf16<0><<<dim3(16, 16), 256, 0, stream>>>(xb, wqT, bq, nullptr, nullptr, nullptr,
                                                       qbb, EMBED, EMBED);
        gemm_bf16<1><<<dim3(16, 16), 256, 0, stream>>>(xb, wkT, bk, nullptr, k_all, nullptr,
                                                       nullptr, EMBED, EMBED);
        gemm_bf16<1><<<dim3(16, 16), 256, 0, stream>>>(xb, wvT, bv, nullptr, v_all, nullptr,
                                                       nullptr, EMBED, EMBED);
        attn_mfma<<<dim3(BATCH * HEADS, 2), 256, 0, stream>>>(qbb, k_all, v_all, ctxb);
        gemm_bf16<2><<<dim3(16, 16), 256, 0, stream>>>(ctxb, woT, bo, hidden, out_hidden,
                                                       nullptr, nullptr, EMBED, EMBED);
        ln_kernel<<<MROWS, 256, 0, stream>>>(out_hidden, ln2_s, ln2_b, fb);
        gemm_bf16<3><<<dim3(64, 16), 256, 0, stream>>>(fb, w1T, b1, nullptr, nullptr, nullptr,
                                                       h1b, FFDIM, EMBED);
        gemm_bf16<4><<<dim3(16, 16), 256, 0, stream>>>(h1b, w2T, b2, out_hidden, out_hidden,
                                                       nullptr, nullptr, EMBED, FFDIM);
    }
}